// Round 9
// baseline (263.698 us; speedup 1.0000x reference)
//
#include <hip/hip_runtime.h>

#define RS2f 0.70710678118654752f

// DPP quad_perm encodings: sel0 | sel1<<2 | sel2<<4 | sel3<<6
#define QP_XOR1 0xB1   // [1,0,3,2]  lane^1 within quad
#define QP_XOR2 0x4E   // [2,3,0,1]  lane^2 within quad
#define QP_BC0  0x00
#define QP_BC1  0x55
#define QP_BC2  0xAA
#define QP_BC3  0xFF

// ds_swizzle BitMode: offset = (xor<<10)|(or<<5)|and ; lane^4 within 32-group
#define SWZ_XOR4 0x101F

typedef float v2f __attribute__((ext_vector_type(2)));

template<int CTRL> __device__ __forceinline__ float dppf(float x) {
  return __int_as_float(__builtin_amdgcn_update_dpp(
      0, __float_as_int(x), CTRL, 0xF, 0xF, true));
}
template<int CTRL> __device__ __forceinline__ v2f dpp2(v2f v) {
  v2f r; r.x = dppf<CTRL>(v.x); r.y = dppf<CTRL>(v.y); return r;
}
__device__ __forceinline__ float swzf4(float x) {
  return __int_as_float(__builtin_amdgcn_ds_swizzle(__float_as_int(x), SWZ_XOR4));
}
__device__ __forceinline__ v2f swz4v(v2f v) {
  v2f r; r.x = swzf4(v.x); r.y = swzf4(v.y); return r;
}

__device__ __forceinline__ float sxor(float x, int sm) {
  return __int_as_float(__float_as_int(x) ^ sm);
}
__device__ __forceinline__ v2f vsplat(float a) { v2f r; r.x = a; r.y = a; return r; }
__device__ __forceinline__ v2f vperp(v2f v) { v2f r; r.x = -v.y; r.y = v.x; return r; }  //  i*v
__device__ __forceinline__ v2f vperc(v2f v) { v2f r; r.x = v.y; r.y = -v.x; return r; }  // -i*v
__device__ __forceinline__ v2f vfma2(float a, v2f b, v2f c) {
  return __builtin_elementwise_fma(vsplat(a), b, c);
}
__device__ __forceinline__ v2f vmul2(float a, v2f b) { return vsplat(a) * b; }

// Closed-form row0 of U = RZ(a4)RY(a3)RZ(a2)RY(a1)RZ(a0)·H  (verified r8).
__device__ __forceinline__ void build_gate(float a0, float a1, float a2, float a3, float a4,
                                           float &w0r, float &w0i, float &w1r, float &w1i) {
  float sBp, cBp, sBm, cBm, sC, cC, sP, cP, sM, cM;
  __sincosf(0.5f * (a1 + a3), &sBp, &cBp);
  __sincosf(0.5f * (a1 - a3), &sBm, &cBm);
  __sincosf(0.5f * a2,        &sC,  &cC);
  __sincosf(0.5f * (a0 + a4), &sP,  &cP);
  __sincosf(0.5f * (a0 - a4), &sM,  &cM);
  float m00r =  cBp * cC, m00i = -cBm * sC;
  float m01r = -sBp * cC, m01i =  sBm * sC;
  float alr = fmaf(m00r, cP,  m00i * sP);
  float ali = fmaf(m00i, cP, -m00r * sP);
  float ber = fmaf(m01r, cM, -m01i * sM);
  float bei = fmaf(m01i, cM,  m01r * sM);
  w0r = RS2f * (alr + ber); w0i = RS2f * (ali + bei);
  w1r = RS2f * (alr - ber); w1i = RS2f * (ali - bei);
}

// Angle picks: lane picks f[5w..5w+4] with w = L&3 (l0/l1/l2 = w==0/1/2).
#define PICK_FULL                                                            \
  a0 = l0 ? P[0][0] : l1 ? P[1][1] : l2 ? P[2][2] : P[3][3];                 \
  a1 = l0 ? P[0][1] : l1 ? P[1][2] : l2 ? P[2][3] : 0.f;                     \
  a2 = l0 ? P[0][2] : l1 ? P[1][3] : l2 ? P[3][0] : 0.f;                     \
  a3 = l0 ? P[0][3] : l1 ? P[2][0] : l2 ? P[3][1] : 0.f;                     \
  a4 = l0 ? P[1][0] : l1 ? P[2][1] : l2 ? P[3][2] : 0.f;

#define PICK_W2                                                              \
  a0 = l0 ? P[0][0] : l1 ? P[2][1] : 0.f;                                    \
  a1 = l0 ? P[0][1] : l1 ? P[3][0] : 0.f;                                    \
  a2 = l0 ? P[1][0] : l1 ? P[3][1] : 0.f;                                    \
  a3 = l0 ? P[1][1] : 0.f;                                                   \
  a4 = l0 ? P[2][0] : 0.f;

#define PICK_H2                                                              \
  a0 = l0 ? P[0][0] : l1 ? P[1][1] : 0.f;                                    \
  a1 = l0 ? P[0][1] : l1 ? P[1][2] : 0.f;                                    \
  a2 = l0 ? P[0][2] : l1 ? P[1][3] : 0.f;                                    \
  a3 = l0 ? P[0][3] : 0.f;                                                   \
  a4 = l0 ? P[1][0] : 0.f;

#define PICK_22                                                              \
  a0 = l0 ? P[0][0] : 0.f;                                                   \
  a1 = l0 ? P[0][1] : 0.f;                                                   \
  a2 = l0 ? P[1][0] : 0.f;                                                   \
  a3 = l0 ? P[1][1] : 0.f;                                                   \
  a4 = 0.f;

// 8-lane apply: amps n = 2L + k (k=0,1). b0=L&4 (wire0, lane^4 swizzle),
// b1=L&2 (wire1, lane^2 DPP), b2=L&1 (wire2, lane^1 DPP), b3=k (wire3, local).
// Cross-wire update (verified r5 pattern): row-bit lane uses ua=-conj(w0),
// ub=conj(w1) via sign masks; row0 lane uses ua=w0, ub=w1.
#define APPLY_AND_FOLD(WIN) do {                                             \
  /* wire 0: partner lane^4 via ds_swizzle, row bit L&4 */                   \
  { float w0r = dppf<QP_BC0>(Wc0), w0i = dppf<QP_BC0>(Wc1);                  \
    float w1r = dppf<QP_BC0>(Wc2), w1i = dppf<QP_BC0>(Wc3);                  \
    float uar = sxor(w0r, smA), uai = w0i;                                   \
    float ubr = w1r,            ubi = sxor(w1i, smA);                        \
    v2f p0 = swz4v(s[0]), p1 = swz4v(s[1]);                                  \
    v2f a0_ = s[0], a1_ = s[1];                                              \
    s[0] = vfma2(uar, a0_, vfma2(uai, vperp(a0_),                            \
                 vfma2(ubr, p0, vmul2(ubi, vperp(p0)))));                    \
    s[1] = vfma2(uar, a1_, vfma2(uai, vperp(a1_),                            \
                 vfma2(ubr, p1, vmul2(ubi, vperp(p1)))));                    \
  }                                                                          \
  /* wire 1: partner lane^2 via DPP, row bit L&2 */                          \
  { float w0r = dppf<QP_BC1>(Wc0), w0i = dppf<QP_BC1>(Wc1);                  \
    float w1r = dppf<QP_BC1>(Wc2), w1i = dppf<QP_BC1>(Wc3);                  \
    float uar = sxor(w0r, smB), uai = w0i;                                   \
    float ubr = w1r,            ubi = sxor(w1i, smB);                        \
    v2f p0 = dpp2<QP_XOR2>(s[0]), p1 = dpp2<QP_XOR2>(s[1]);                  \
    v2f a0_ = s[0], a1_ = s[1];                                              \
    s[0] = vfma2(uar, a0_, vfma2(uai, vperp(a0_),                            \
                 vfma2(ubr, p0, vmul2(ubi, vperp(p0)))));                    \
    s[1] = vfma2(uar, a1_, vfma2(uai, vperp(a1_),                            \
                 vfma2(ubr, p1, vmul2(ubi, vperp(p1)))));                    \
  }                                                                          \
  /* wire 2: partner lane^1 via DPP, row bit L&1 */                          \
  { float w0r = dppf<QP_BC2>(Wc0), w0i = dppf<QP_BC2>(Wc1);                  \
    float w1r = dppf<QP_BC2>(Wc2), w1i = dppf<QP_BC2>(Wc3);                  \
    float uar = sxor(w0r, smC), uai = w0i;                                   \
    float ubr = w1r,            ubi = sxor(w1i, smC);                        \
    v2f p0 = dpp2<QP_XOR1>(s[0]), p1 = dpp2<QP_XOR1>(s[1]);                  \
    v2f a0_ = s[0], a1_ = s[1];                                              \
    s[0] = vfma2(uar, a0_, vfma2(uai, vperp(a0_),                            \
                 vfma2(ubr, p0, vmul2(ubi, vperp(p0)))));                    \
    s[1] = vfma2(uar, a1_, vfma2(uai, vperp(a1_),                            \
                 vfma2(ubr, p1, vmul2(ubi, vperp(p1)))));                    \
  }                                                                          \
  /* wire 3: local pair (verified r8 wire3 form) */                          \
  { float w0r = dppf<QP_BC3>(Wc0), w0i = dppf<QP_BC3>(Wc1);                  \
    float w1r = dppf<QP_BC3>(Wc2), w1i = dppf<QP_BC3>(Wc3);                  \
    float nw0r = -w0r, nw0i = -w0i;                                          \
    v2f lo = s[0], hi = s[1];                                                \
    s[0] = vfma2(w0r, lo, vfma2(w0i, vperp(lo),                              \
                 vfma2(w1r, hi, vmul2(w1i, vperp(hi)))));                    \
    s[1] = vfma2(w1r, lo, vfma2(w1i, vperc(lo),                              \
                 vfma2(nw0r, hi, vmul2(nw0i, vperc(hi)))));                  \
  }                                                                          \
  /* CRZ ring diagonal */                                                    \
  s[0] = vfma2(cz0, s[0], vmul2(sz0, vperp(s[0])));                          \
  s[1] = vfma2(cz1, s[1], vmul2(sz1, vperp(s[1])));                          \
  /* Ry wire0 (lane^4 swizzle) */                                            \
  { v2f p0 = swz4v(s[0]), p1 = swz4v(s[1]);                                  \
    s[0] = vfma2(cry, s[0], vmul2(sgnA, p0));                                \
    s[1] = vfma2(cry, s[1], vmul2(sgnA, p1)); }                              \
  /* Ry wire1 (lane^2 DPP) */                                                \
  { v2f p0 = dpp2<QP_XOR2>(s[0]), p1 = dpp2<QP_XOR2>(s[1]);                  \
    s[0] = vfma2(cry, s[0], vmul2(sgnB, p0));                                \
    s[1] = vfma2(cry, s[1], vmul2(sgnB, p1)); }                              \
  /* Ry wire2 (lane^1 DPP) */                                                \
  { v2f p0 = dpp2<QP_XOR1>(s[0]), p1 = dpp2<QP_XOR1>(s[1]);                  \
    s[0] = vfma2(cry, s[0], vmul2(sgnC, p0));                                \
    s[1] = vfma2(cry, s[1], vmul2(sgnC, p1)); }                              \
  /* Ry wire3 (local) */                                                     \
  { v2f lo = s[0], hi = s[1];                                                \
    s[0] = vfma2(cry, lo, vmul2(nsry, hi));                                  \
    s[1] = vfma2(sry, lo, vmul2(cry, hi)); }                                 \
  /* Z expectations + 8-lane butterfly (DPP xor1, xor2, swizzle xor4) */     \
  { v2f q0 = s[0]*s[0], q1 = s[1]*s[1];                                      \
    float p0 = q0.x + q0.y, p1 = q1.x + q1.y;                                \
    float t_ = p0 + p1;                                                      \
    float o0 = sxor(t_, smA);                                                \
    float o1 = sxor(t_, smB);                                                \
    float o2 = sxor(t_, smC);                                                \
    float o3 = p0 - p1;                                                      \
    o0 += dppf<QP_XOR1>(o0); o1 += dppf<QP_XOR1>(o1);                        \
    o2 += dppf<QP_XOR1>(o2); o3 += dppf<QP_XOR1>(o3);                        \
    o0 += dppf<QP_XOR2>(o0); o1 += dppf<QP_XOR2>(o1);                        \
    o2 += dppf<QP_XOR2>(o2); o3 += dppf<QP_XOR2>(o3);                        \
    o0 += swzf4(o0); o1 += swzf4(o1); o2 += swzf4(o2); o3 += swzf4(o3);      \
    const int win4_ = (WIN) * 4;                                             \
    float4 wv0 = *(const float4*)(swl + win4_);                              \
    float4 wv1 = *(const float4*)(swl + 784 + win4_);                        \
    float4 wv2 = *(const float4*)(swl + off2 + win4_);                       \
    h1[0] = fmaf(wv0.x, o0, fmaf(wv0.y, o1, fmaf(wv0.z, o2, fmaf(wv0.w, o3, h1[0])))); \
    h1[1] = fmaf(wv1.x, o0, fmaf(wv1.y, o1, fmaf(wv1.z, o2, fmaf(wv1.w, o3, h1[1])))); \
    h1[2] = fmaf(wv2.x, o0, fmaf(wv2.y, o1, fmaf(wv2.z, o2, fmaf(wv2.w, o3, h1[2])))); \
  }                                                                          \
} while (0)

#define ROTATE_W  Wc0 = Wn0; Wc1 = Wn1; Wc2 = Wn2; Wc3 = Wn3;

__global__ void __launch_bounds__(256)
quanv_kernel(const float* __restrict__ x,
             const float* __restrict__ crz_t,
             const float* __restrict__ ry_t,
             const float* __restrict__ fc1_w,
             const float* __restrict__ fc1_b,
             const float* __restrict__ fc2_w,
             const float* __restrict__ fc2_b,
             float* __restrict__ out, int B)
{
  __shared__ float sw[20 * 784];
  const int tid = threadIdx.x;
  for (int i = tid; i < (20 * 784) / 4; i += 256)
    ((float4*)sw)[i] = ((const float4*)fc1_w)[i];
  __syncthreads();

  const int L = tid & 7;                        // lane within 8-lane group
  const int b = (blockIdx.x * 256 + tid) >> 3;  // element id
  if (b >= B) return;
  const float* img = x + (size_t)b * 784;
  const int w_ = L & 3;
  const bool l0 = (w_ == 0), l1 = (w_ == 1), l2 = (w_ == 2);
  const int hiH = L >> 2;

  // ---- uniform scalar-derived constants ----
  const float theta = crz_t[0];
  const float ryt   = ry_t[0];
  float cry, sry;
  __sincosf(0.5f * ryt, &sry, &cry);
  const float nsry = -sry;
  const float sgnA = (L & 4) ? sry : -sry;   // Ry wire0 partner sign (bit b0)
  const float sgnB = (L & 2) ? sry : -sry;   // wire1 (bit b1)
  const float sgnC = (L & 1) ? sry : -sry;   // wire2 (bit b2)
  const int smA = (L & 4) ? (int)0x80000000 : 0;
  const int smB = (L & 2) ? (int)0x80000000 : 0;
  const int smC = (L & 1) ? (int)0x80000000 : 0;

  // CRZ ring signs for this lane's amps n=2L (k=0) and n=2L+1 (k=1)
  // kCrz = {0,-1,-1,0,-1,-2,0,1,-1,0,-2,1,0,1,1,4}
  const float gk0 = (L==1||L==2||L==4) ? -1.f : (L==5) ? -2.f : (L==7) ? 1.f : 0.f;
  const float gk1 = (L==0) ? -1.f : (L==2) ? -2.f :
                    (L==3||L==5||L==6) ? 1.f : (L==7) ? 4.f : 0.f;
  float cz0, sz0, cz1, sz1;
  __sincosf(0.5f*theta*gk0, &sz0, &cz0);
  __sincosf(0.5f*theta*gk1, &sz1, &cz1);

  // state: 2 amps/lane, packed (re,im)
  v2f s[2];
  s[0].x = 0.f; s[0].y = 0.f; s[1].x = 0.f; s[1].y = 0.f;
  if (L == 0) s[0].x = 1.f;

  // fc1 rows: low half-lanes rows 5w..5w+2, high half rows 5w+3..5w+4 (+dup)
  const int row0 = 5 * w_ + (hiH ? 3 : 0);
  const int off2 = hiH ? 784 : 1568;           // j=2 duplicates j=1 for hi half
  float h1[3];
  h1[0] = 0.f; h1[1] = 0.f; h1[2] = 0.f;
  const float* swl = sw + row0 * 784;

  float P[4][4];
  float a0, a1, a2, a3, a4;
  float Wc0, Wc1, Wc2, Wc3, Wn0, Wn1, Wn2, Wn3;

  // ================= main rows: wi = 0..12 (h = 4 always) =================
#pragma unroll 1
  for (int wi = 0; wi < 13; ++wi) {
    const float* imgw = img + (2 * wi) * 28;

    // peel wj = 0: fresh load + build only
#pragma unroll
    for (int r = 0; r < 4; ++r) {
      float4 v = *(const float4*)(imgw + r * 28);
      P[r][0]=v.x; P[r][1]=v.y; P[r][2]=v.z; P[r][3]=v.w;
    }
    PICK_FULL;
    build_gate(a0, a1, a2, a3, a4, Wc0, Wc1, Wc2, Wc3);

    // hot loop: wj = 1..12 — branch-free body, build(wj) || apply(wj-1)
#pragma unroll 1
    for (int wj = 1; wj <= 12; ++wj) {
      const int c0 = 2 * wj + 2;                 // 4..26, always in-bounds
#pragma unroll
      for (int r = 0; r < 4; ++r) {
        P[r][0] = P[r][2]; P[r][1] = P[r][3];
        float2 v = *(const float2*)(imgw + r * 28 + c0);
        P[r][2] = v.x; P[r][3] = v.y;
      }
      PICK_FULL;
      build_gate(a0, a1, a2, a3, a4, Wn0, Wn1, Wn2, Wn3);
      APPLY_AND_FOLD(wi * 14 + wj - 1);
      ROTATE_W;
    }

    // peel wj = 13
#pragma unroll
    for (int r = 0; r < 4; ++r) {
      P[r][0] = P[r][2]; P[r][1] = P[r][3]; P[r][2] = 0.f; P[r][3] = 0.f;
    }
    PICK_W2;
    build_gate(a0, a1, a2, a3, a4, Wn0, Wn1, Wn2, Wn3);
    APPLY_AND_FOLD(wi * 14 + 12);
    ROTATE_W;
    APPLY_AND_FOLD(wi * 14 + 13);
  }

  // ================= tail row: wi = 13 (h = 2) =================
  {
    const float* imgw = img + 26 * 28;
#pragma unroll
    for (int r = 0; r < 2; ++r) {
      float4 v = *(const float4*)(imgw + r * 28);
      P[r][0]=v.x; P[r][1]=v.y; P[r][2]=v.z; P[r][3]=v.w;
    }
#pragma unroll
    for (int r = 2; r < 4; ++r) { P[r][0]=0.f; P[r][1]=0.f; P[r][2]=0.f; P[r][3]=0.f; }
    PICK_H2;
    build_gate(a0, a1, a2, a3, a4, Wc0, Wc1, Wc2, Wc3);

#pragma unroll 1
    for (int wj = 1; wj <= 12; ++wj) {
      const int c0 = 2 * wj + 2;
      P[0][0]=P[0][2]; P[0][1]=P[0][3];
      P[1][0]=P[1][2]; P[1][1]=P[1][3];
      float2 v0 = *(const float2*)(imgw + c0);       P[0][2]=v0.x; P[0][3]=v0.y;
      float2 v1 = *(const float2*)(imgw + 28 + c0);  P[1][2]=v1.x; P[1][3]=v1.y;
      PICK_H2;
      build_gate(a0, a1, a2, a3, a4, Wn0, Wn1, Wn2, Wn3);
      APPLY_AND_FOLD(182 + wj - 1);
      ROTATE_W;
    }

    P[0][0]=P[0][2]; P[0][1]=P[0][3]; P[0][2]=0.f; P[0][3]=0.f;
    P[1][0]=P[1][2]; P[1][1]=P[1][3]; P[1][2]=0.f; P[1][3]=0.f;
    PICK_22;
    build_gate(a0, a1, a2, a3, a4, Wn0, Wn1, Wn2, Wn3);
    APPLY_AND_FOLD(182 + 12);
    ROTATE_W;
    APPLY_AND_FOLD(182 + 13);
  }

  // ---- epilogue: bias + leaky relu + fc2 partial, reduce over 8 lanes ----
  float pa = 0.f, pb = 0.f;
  {
    int r = row0;
    float v = h1[0] + fc1_b[r];
    v = (v > 0.f) ? v : 0.1f * v;
    pa = fmaf(fc2_w[r], v, pa); pb = fmaf(fc2_w[20 + r], v, pb);
  }
  {
    int r = row0 + 1;
    float v = h1[1] + fc1_b[r];
    v = (v > 0.f) ? v : 0.1f * v;
    pa = fmaf(fc2_w[r], v, pa); pb = fmaf(fc2_w[20 + r], v, pb);
  }
  if (!hiH) {                                   // 3rd row only for low half
    int r = row0 + 2;
    float v = h1[2] + fc1_b[r];
    v = (v > 0.f) ? v : 0.1f * v;
    pa = fmaf(fc2_w[r], v, pa); pb = fmaf(fc2_w[20 + r], v, pb);
  }
  pa += dppf<QP_XOR1>(pa); pa += dppf<QP_XOR2>(pa); pa += swzf4(pa);
  pb += dppf<QP_XOR1>(pb); pb += dppf<QP_XOR2>(pb); pb += swzf4(pb);
  if (L == 0) {
    float2 res; res.x = pa + fc2_b[0]; res.y = pb + fc2_b[1];
    *(float2*)(out + (size_t)b * 2) = res;
  }
}

extern "C" void kernel_launch(void* const* d_in, const int* in_sizes, int n_in,
                              void* d_out, int out_size, void* d_ws, size_t ws_size,
                              hipStream_t stream) {
  const float* x      = (const float*)d_in[0];
  const float* crz_t  = (const float*)d_in[1];
  const float* ry_t   = (const float*)d_in[2];
  const float* fc1_w  = (const float*)d_in[3];
  const float* fc1_b  = (const float*)d_in[4];
  const float* fc2_w  = (const float*)d_in[5];
  const float* fc2_b  = (const float*)d_in[6];
  float* out = (float*)d_out;
  const int B = in_sizes[0] / 784;
  const int grid = (B * 8 + 255) / 256;
  quanv_kernel<<<grid, 256, 0, stream>>>(x, crz_t, ry_t, fc1_w, fc1_b,
                                         fc2_w, fc2_b, out, B);
}

// Round 10
// 226.254 us; speedup vs baseline: 1.1655x; 1.1655x over previous
//
#include <hip/hip_runtime.h>

#define RS2f 0.70710678118654752f

// DPP quad_perm encodings: sel0 | sel1<<2 | sel2<<4 | sel3<<6
#define QP_XOR1 0xB1   // [1,0,3,2]
#define QP_XOR2 0x4E   // [2,3,0,1]
#define QP_BC0  0x00
#define QP_BC1  0x55
#define QP_BC2  0xAA
#define QP_BC3  0xFF

typedef float v2f __attribute__((ext_vector_type(2)));

template<int CTRL> __device__ __forceinline__ float dppf(float x) {
  return __int_as_float(__builtin_amdgcn_update_dpp(
      0, __float_as_int(x), CTRL, 0xF, 0xF, true));
}
template<int CTRL> __device__ __forceinline__ v2f dpp2(v2f v) {
  v2f r; r.x = dppf<CTRL>(v.x); r.y = dppf<CTRL>(v.y); return r;
}

__device__ __forceinline__ float sxor(float x, int sm) {
  return __int_as_float(__float_as_int(x) ^ sm);
}
__device__ __forceinline__ v2f vsplat(float a) { v2f r; r.x = a; r.y = a; return r; }
__device__ __forceinline__ v2f vperp(v2f v) { v2f r; r.x = -v.y; r.y = v.x; return r; }  //  i*v
__device__ __forceinline__ v2f vperc(v2f v) { v2f r; r.x = v.y; r.y = -v.x; return r; }  // -i*v
__device__ __forceinline__ v2f vfma2(float a, v2f b, v2f c) {
  return __builtin_elementwise_fma(vsplat(a), b, c);
}
__device__ __forceinline__ v2f vmul2(float a, v2f b) { return vsplat(a) * b; }

// Closed-form row0 of U = RZ(a4)RY(a3)RZ(a2)RY(a1)RZ(a0)·H  (verified r8).
__device__ __forceinline__ void build_gate(float a0, float a1, float a2, float a3, float a4,
                                           float &w0r, float &w0i, float &w1r, float &w1i) {
  float sBp, cBp, sBm, cBm, sC, cC, sP, cP, sM, cM;
  __sincosf(0.5f * (a1 + a3), &sBp, &cBp);
  __sincosf(0.5f * (a1 - a3), &sBm, &cBm);
  __sincosf(0.5f * a2,        &sC,  &cC);
  __sincosf(0.5f * (a0 + a4), &sP,  &cP);
  __sincosf(0.5f * (a0 - a4), &sM,  &cM);
  float m00r =  cBp * cC, m00i = -cBm * sC;
  float m01r = -sBp * cC, m01i =  sBm * sC;
  float alr = fmaf(m00r, cP,  m00i * sP);
  float ali = fmaf(m00i, cP, -m00r * sP);
  float ber = fmaf(m01r, cM, -m01i * sM);
  float bei = fmaf(m01i, cM,  m01r * sM);
  w0r = RS2f * (alr + ber); w0i = RS2f * (ali + bei);
  w1r = RS2f * (alr - ber); w1i = RS2f * (ali - bei);
}

#define PICK_FULL                                                            \
  a0 = l0 ? P[0][0] : l1 ? P[1][1] : l2 ? P[2][2] : P[3][3];                 \
  a1 = l0 ? P[0][1] : l1 ? P[1][2] : l2 ? P[2][3] : 0.f;                     \
  a2 = l0 ? P[0][2] : l1 ? P[1][3] : l2 ? P[3][0] : 0.f;                     \
  a3 = l0 ? P[0][3] : l1 ? P[2][0] : l2 ? P[3][1] : 0.f;                     \
  a4 = l0 ? P[1][0] : l1 ? P[2][1] : l2 ? P[3][2] : 0.f;

#define PICK_W2                                                              \
  a0 = l0 ? P[0][0] : l1 ? P[2][1] : 0.f;                                    \
  a1 = l0 ? P[0][1] : l1 ? P[3][0] : 0.f;                                    \
  a2 = l0 ? P[1][0] : l1 ? P[3][1] : 0.f;                                    \
  a3 = l0 ? P[1][1] : 0.f;                                                   \
  a4 = l0 ? P[2][0] : 0.f;

#define PICK_H2                                                              \
  a0 = l0 ? P[0][0] : l1 ? P[1][1] : 0.f;                                    \
  a1 = l0 ? P[0][1] : l1 ? P[1][2] : 0.f;                                    \
  a2 = l0 ? P[0][2] : l1 ? P[1][3] : 0.f;                                    \
  a3 = l0 ? P[0][3] : 0.f;                                                   \
  a4 = l0 ? P[1][0] : 0.f;

#define PICK_22                                                              \
  a0 = l0 ? P[0][0] : 0.f;                                                   \
  a1 = l0 ? P[0][1] : 0.f;                                                   \
  a2 = l0 ? P[1][0] : 0.f;                                                   \
  a3 = l0 ? P[1][1] : 0.f;                                                   \
  a4 = 0.f;

// Apply gate (Wc) to state + CRZ + Ry + Z expectations; emits PRE-butterfly
// per-lane o-values into np0..np3. Verified r8 math, readout split off.
#define APPLY_Z do {                                                         \
  { float w0r = dppf<QP_BC0>(Wc0), w0i = dppf<QP_BC0>(Wc1);                  \
    float w1r = dppf<QP_BC0>(Wc2), w1i = dppf<QP_BC0>(Wc3);                  \
    float uar = sxor(w0r, sm0), uai = w0i;                                   \
    float ubr = w1r,            ubi = sxor(w1i, sm0);                        \
    _Pragma("unroll")                                                        \
    for (int k = 0; k < 4; ++k) {                                            \
      v2f p = dpp2<QP_XOR2>(s[k]);                                           \
      v2f a = s[k];                                                          \
      s[k] = vfma2(uar, a, vfma2(uai, vperp(a),                              \
                   vfma2(ubr, p, vmul2(ubi, vperp(p)))));                    \
    } }                                                                      \
  { float w0r = dppf<QP_BC1>(Wc0), w0i = dppf<QP_BC1>(Wc1);                  \
    float w1r = dppf<QP_BC1>(Wc2), w1i = dppf<QP_BC1>(Wc3);                  \
    float uar = sxor(w0r, sm1), uai = w0i;                                   \
    float ubr = w1r,            ubi = sxor(w1i, sm1);                        \
    _Pragma("unroll")                                                        \
    for (int k = 0; k < 4; ++k) {                                            \
      v2f p = dpp2<QP_XOR1>(s[k]);                                           \
      v2f a = s[k];                                                          \
      s[k] = vfma2(uar, a, vfma2(uai, vperp(a),                              \
                   vfma2(ubr, p, vmul2(ubi, vperp(p)))));                    \
    } }                                                                      \
  { float w0r = dppf<QP_BC2>(Wc0), w0i = dppf<QP_BC2>(Wc1);                  \
    float w1r = dppf<QP_BC2>(Wc2), w1i = dppf<QP_BC2>(Wc3);                  \
    float nw0r = -w0r, nw0i = -w0i;                                          \
    _Pragma("unroll")                                                        \
    for (int k = 0; k < 2; ++k) {                                            \
      v2f lo = s[k], hi = s[k+2];                                            \
      s[k]   = vfma2(w0r, lo, vfma2(w0i, vperp(lo),                          \
                     vfma2(w1r, hi, vmul2(w1i, vperp(hi)))));                \
      s[k+2] = vfma2(w1r, lo, vfma2(w1i, vperc(lo),                          \
                     vfma2(nw0r, hi, vmul2(nw0i, vperc(hi)))));              \
    } }                                                                      \
  { float w0r = dppf<QP_BC3>(Wc0), w0i = dppf<QP_BC3>(Wc1);                  \
    float w1r = dppf<QP_BC3>(Wc2), w1i = dppf<QP_BC3>(Wc3);                  \
    float nw0r = -w0r, nw0i = -w0i;                                          \
    _Pragma("unroll")                                                        \
    for (int k = 0; k < 4; k += 2) {                                         \
      v2f lo = s[k], hi = s[k+1];                                            \
      s[k]   = vfma2(w0r, lo, vfma2(w0i, vperp(lo),                          \
                     vfma2(w1r, hi, vmul2(w1i, vperp(hi)))));                \
      s[k+1] = vfma2(w1r, lo, vfma2(w1i, vperc(lo),                          \
                     vfma2(nw0r, hi, vmul2(nw0i, vperc(hi)))));              \
    } }                                                                      \
  _Pragma("unroll")                                                          \
  for (int k = 0; k < 4; ++k)                                                \
    s[k] = vfma2(czk[k], s[k], vmul2(szk[k], vperp(s[k])));                  \
  _Pragma("unroll")                                                          \
  for (int k = 0; k < 4; ++k) {                                              \
    v2f p = dpp2<QP_XOR2>(s[k]);                                             \
    s[k] = vfma2(cry, s[k], vmul2(sgn0, p));                                 \
  }                                                                          \
  _Pragma("unroll")                                                          \
  for (int k = 0; k < 4; ++k) {                                              \
    v2f p = dpp2<QP_XOR1>(s[k]);                                             \
    s[k] = vfma2(cry, s[k], vmul2(sgn1, p));                                 \
  }                                                                          \
  _Pragma("unroll")                                                          \
  for (int k = 0; k < 2; ++k) {                                              \
    v2f lo = s[k], hi = s[k+2];                                              \
    s[k]   = vfma2(cry, lo, vmul2(nsry, hi));                                \
    s[k+2] = vfma2(sry, lo, vmul2(cry, hi));                                 \
  }                                                                          \
  _Pragma("unroll")                                                          \
  for (int k = 0; k < 4; k += 2) {                                           \
    v2f lo = s[k], hi = s[k+1];                                              \
    s[k]   = vfma2(cry, lo, vmul2(nsry, hi));                                \
    s[k+1] = vfma2(sry, lo, vmul2(cry, hi));                                 \
  }                                                                          \
  { v2f q0 = s[0]*s[0], q1 = s[1]*s[1], q2 = s[2]*s[2], q3 = s[3]*s[3];      \
    float p0 = q0.x + q0.y, p1 = q1.x + q1.y;                                \
    float p2 = q2.x + q2.y, p3 = q3.x + q3.y;                                \
    float s01 = p0 + p1, s23 = p2 + p3;                                      \
    float t_  = s01 + s23;                                                   \
    np0 = sxor(t_, sm0);                                                     \
    np1 = sxor(t_, sm1);                                                     \
    np2 = s01 - s23;                                                         \
    np3 = (p0 - p1) + (p2 - p3);                                             \
  }                                                                          \
} while (0)

// Deferred readout: butterfly + fc1 fold for the PENDING window (pd*, pdWin).
// Independent of the current build/apply — pure latency filler.
#define BF_FOLD do {                                                         \
  float o0 = pd0, o1 = pd1, o2 = pd2, o3 = pd3;                              \
  o0 += dppf<QP_XOR1>(o0); o0 += dppf<QP_XOR2>(o0);                          \
  o1 += dppf<QP_XOR1>(o1); o1 += dppf<QP_XOR2>(o1);                          \
  o2 += dppf<QP_XOR1>(o2); o2 += dppf<QP_XOR2>(o2);                          \
  o3 += dppf<QP_XOR1>(o3); o3 += dppf<QP_XOR2>(o3);                          \
  const float* wp = swl + pdWin * 4;                                         \
  float4 wv0 = *(const float4*)(wp);                                         \
  float4 wv1 = *(const float4*)(wp + 784);                                   \
  float4 wv2 = *(const float4*)(wp + 1568);                                  \
  float4 wv3 = *(const float4*)(wp + 2352);                                  \
  float4 wv4 = *(const float4*)(wp + 3136);                                  \
  h1[0] = fmaf(wv0.x, o0, fmaf(wv0.y, o1, fmaf(wv0.z, o2, fmaf(wv0.w, o3, h1[0])))); \
  h1[1] = fmaf(wv1.x, o0, fmaf(wv1.y, o1, fmaf(wv1.z, o2, fmaf(wv1.w, o3, h1[1])))); \
  h1[2] = fmaf(wv2.x, o0, fmaf(wv2.y, o1, fmaf(wv2.z, o2, fmaf(wv2.w, o3, h1[2])))); \
  h1[3] = fmaf(wv3.x, o0, fmaf(wv3.y, o1, fmaf(wv3.z, o2, fmaf(wv3.w, o3, h1[3])))); \
  h1[4] = fmaf(wv4.x, o0, fmaf(wv4.y, o1, fmaf(wv4.z, o2, fmaf(wv4.w, o3, h1[4])))); \
} while (0)

#define SHIFT_PEND(WIN)  pd0 = np0; pd1 = np1; pd2 = np2; pd3 = np3; pdWin = (WIN);
#define ROTATE_W  Wc0 = Wn0; Wc1 = Wn1; Wc2 = Wn2; Wc3 = Wn3;

__global__ void __launch_bounds__(256)
quanv_kernel(const float* __restrict__ x,
             const float* __restrict__ crz_t,
             const float* __restrict__ ry_t,
             const float* __restrict__ fc1_w,
             const float* __restrict__ fc1_b,
             const float* __restrict__ fc2_w,
             const float* __restrict__ fc2_b,
             float* __restrict__ out, int B)
{
  __shared__ float sw[20 * 784];
  const int tid = threadIdx.x;
  for (int i = tid; i < (20 * 784) / 4; i += 256)
    ((float4*)sw)[i] = ((const float4*)fc1_w)[i];
  __syncthreads();

  const int l = tid & 3;                       // lane within 4-lane group
  const int b = (blockIdx.x * 256 + tid) >> 2; // element id
  if (b >= B) return;
  const float* img = x + (size_t)b * 784;
  const bool l0 = (l == 0), l1 = (l == 1), l2 = (l == 2);

  // ---- uniform scalar-derived constants ----
  const float theta = crz_t[0];
  const float ryt   = ry_t[0];
  float cry, sry;
  __sincosf(0.5f * ryt, &sry, &cry);
  const float nsry = -sry;
  const float sgn0 = (l & 2) ? sry : -sry;
  const float sgn1 = (l & 1) ? sry : -sry;
  const int sm0 = (l & 2) ? (int)0x80000000 : 0;
  const int sm1 = (l & 1) ? (int)0x80000000 : 0;

  float g0,g1,g2,g3;
  if      (l == 0) { g0= 0.f; g1=-1.f; g2=-1.f; g3=0.f; }
  else if (l == 1) { g0=-1.f; g1=-2.f; g2= 0.f; g3=1.f; }
  else if (l == 2) { g0=-1.f; g1= 0.f; g2=-2.f; g3=1.f; }
  else             { g0= 0.f; g1= 1.f; g2= 1.f; g3=4.f; }
  float czk[4], szk[4];
  __sincosf(0.5f*theta*g0, &szk[0], &czk[0]);
  __sincosf(0.5f*theta*g1, &szk[1], &czk[1]);
  __sincosf(0.5f*theta*g2, &szk[2], &czk[2]);
  __sincosf(0.5f*theta*g3, &szk[3], &czk[3]);

  // state: amp n = 4*l + k; s[k] = (re, im) packed
  v2f s[4];
#pragma unroll
  for (int k = 0; k < 4; ++k) { s[k].x = 0.f; s[k].y = 0.f; }
  if (l == 0) s[0].x = 1.f;

  float h1[5];
#pragma unroll
  for (int j = 0; j < 5; ++j) h1[j] = 0.f;
  const float* swl = sw + 5 * l * 784;

  float P[4][4];
  float a0, a1, a2, a3, a4;
  float Wc0, Wc1, Wc2, Wc3, Wn0, Wn1, Wn2, Wn3;
  float np0, np1, np2, np3;
  // pending readout pipeline — seeded with zeros (fold of 0 is a no-op)
  float pd0 = 0.f, pd1 = 0.f, pd2 = 0.f, pd3 = 0.f;
  int pdWin = 0;

  // ================= main rows: wi = 0..12 (h = 4 always) =================
#pragma unroll 1
  for (int wi = 0; wi < 13; ++wi) {
    const float* imgw = img + (2 * wi) * 28;

    // peel wj = 0: fresh load + build only (prev row's pending carries over)
#pragma unroll
    for (int r = 0; r < 4; ++r) {
      float4 v = *(const float4*)(imgw + r * 28);
      P[r][0]=v.x; P[r][1]=v.y; P[r][2]=v.z; P[r][3]=v.w;
    }
    PICK_FULL;
    build_gate(a0, a1, a2, a3, a4, Wc0, Wc1, Wc2, Wc3);

    // hot loop: wj = 1..12 — branch-free; unroll 2 => one BB per 2 windows.
    // Body: build(wj) || apply(wj-1) || deferred butterfly+fold(wj-2).
#pragma unroll 2
    for (int wj = 1; wj <= 12; ++wj) {
      const int c0 = 2 * wj + 2;                 // 4..26, always in-bounds
#pragma unroll
      for (int r = 0; r < 4; ++r) {
        P[r][0] = P[r][2]; P[r][1] = P[r][3];
        float2 v = *(const float2*)(imgw + r * 28 + c0);
        P[r][2] = v.x; P[r][3] = v.y;
      }
      PICK_FULL;
      build_gate(a0, a1, a2, a3, a4, Wn0, Wn1, Wn2, Wn3);
      APPLY_Z;                                   // window wj-1 -> np
      BF_FOLD;                                   // window wj-2 (or older)
      SHIFT_PEND(wi * 14 + wj - 1);
      ROTATE_W;
    }

    // peel wj = 13
#pragma unroll
    for (int r = 0; r < 4; ++r) {
      P[r][0] = P[r][2]; P[r][1] = P[r][3]; P[r][2] = 0.f; P[r][3] = 0.f;
    }
    PICK_W2;
    build_gate(a0, a1, a2, a3, a4, Wn0, Wn1, Wn2, Wn3);
    APPLY_Z;                                     // window 12
    BF_FOLD;                                     // window 11
    SHIFT_PEND(wi * 14 + 12);
    ROTATE_W;
    APPLY_Z;                                     // window 13
    BF_FOLD;                                     // window 12
    SHIFT_PEND(wi * 14 + 13);
  }

  // ================= tail row: wi = 13 (h = 2) =================
  {
    const float* imgw = img + 26 * 28;
#pragma unroll
    for (int r = 0; r < 2; ++r) {
      float4 v = *(const float4*)(imgw + r * 28);
      P[r][0]=v.x; P[r][1]=v.y; P[r][2]=v.z; P[r][3]=v.w;
    }
#pragma unroll
    for (int r = 2; r < 4; ++r) { P[r][0]=0.f; P[r][1]=0.f; P[r][2]=0.f; P[r][3]=0.f; }
    PICK_H2;
    build_gate(a0, a1, a2, a3, a4, Wc0, Wc1, Wc2, Wc3);

#pragma unroll 2
    for (int wj = 1; wj <= 12; ++wj) {
      const int c0 = 2 * wj + 2;
      P[0][0]=P[0][2]; P[0][1]=P[0][3];
      P[1][0]=P[1][2]; P[1][1]=P[1][3];
      float2 v0 = *(const float2*)(imgw + c0);       P[0][2]=v0.x; P[0][3]=v0.y;
      float2 v1 = *(const float2*)(imgw + 28 + c0);  P[1][2]=v1.x; P[1][3]=v1.y;
      PICK_H2;
      build_gate(a0, a1, a2, a3, a4, Wn0, Wn1, Wn2, Wn3);
      APPLY_Z;
      BF_FOLD;
      SHIFT_PEND(182 + wj - 1);
      ROTATE_W;
    }

    P[0][0]=P[0][2]; P[0][1]=P[0][3]; P[0][2]=0.f; P[0][3]=0.f;
    P[1][0]=P[1][2]; P[1][1]=P[1][3]; P[1][2]=0.f; P[1][3]=0.f;
    PICK_22;
    build_gate(a0, a1, a2, a3, a4, Wn0, Wn1, Wn2, Wn3);
    APPLY_Z;                                     // window 194
    BF_FOLD;                                     // window 193
    SHIFT_PEND(182 + 12);
    ROTATE_W;
    APPLY_Z;                                     // window 195
    BF_FOLD;                                     // window 194
    SHIFT_PEND(182 + 13);
  }

  // drain the pipeline: fold window 195
  BF_FOLD;

  // ---- epilogue: bias + leaky relu + fc2, reduce over group ----
  float pa = 0.f, pb = 0.f;
#pragma unroll
  for (int j = 0; j < 5; ++j) {
    const int r = 5 * l + j;
    float v = h1[j] + fc1_b[r];
    v = (v > 0.f) ? v : 0.1f * v;
    pa = fmaf(fc2_w[r],      v, pa);
    pb = fmaf(fc2_w[20 + r], v, pb);
  }
  pa += dppf<QP_XOR1>(pa); pa += dppf<QP_XOR2>(pa);
  pb += dppf<QP_XOR1>(pb); pb += dppf<QP_XOR2>(pb);
  if (l == 0) {
    float2 res; res.x = pa + fc2_b[0]; res.y = pb + fc2_b[1];
    *(float2*)(out + (size_t)b * 2) = res;
  }
}

extern "C" void kernel_launch(void* const* d_in, const int* in_sizes, int n_in,
                              void* d_out, int out_size, void* d_ws, size_t ws_size,
                              hipStream_t stream) {
  const float* x      = (const float*)d_in[0];
  const float* crz_t  = (const float*)d_in[1];
  const float* ry_t   = (const float*)d_in[2];
  const float* fc1_w  = (const float*)d_in[3];
  const float* fc1_b  = (const float*)d_in[4];
  const float* fc2_w  = (const float*)d_in[5];
  const float* fc2_b  = (const float*)d_in[6];
  float* out = (float*)d_out;
  const int B = in_sizes[0] / 784;
  const int grid = (B * 4 + 255) / 256;
  quanv_kernel<<<grid, 256, 0, stream>>>(x, crz_t, ry_t, fc1_w, fc1_b,
                                         fc2_w, fc2_b, out, B);
}

// Round 11
// 225.127 us; speedup vs baseline: 1.1713x; 1.0050x over previous
//
#include <hip/hip_runtime.h>

#define RS2f 0.70710678118654752f

// DPP quad_perm encodings: sel0 | sel1<<2 | sel2<<4 | sel3<<6
#define QP_XOR1 0xB1   // [1,0,3,2]
#define QP_XOR2 0x4E   // [2,3,0,1]
#define QP_BC0  0x00
#define QP_BC1  0x55
#define QP_BC2  0xAA
#define QP_BC3  0xFF

typedef float v2f __attribute__((ext_vector_type(2)));

template<int CTRL> __device__ __forceinline__ float dppf(float x) {
  return __int_as_float(__builtin_amdgcn_update_dpp(
      0, __float_as_int(x), CTRL, 0xF, 0xF, true));
}
template<int CTRL> __device__ __forceinline__ v2f dpp2(v2f v) {
  v2f r; r.x = dppf<CTRL>(v.x); r.y = dppf<CTRL>(v.y); return r;
}

__device__ __forceinline__ float sxor(float x, int sm) {
  return __int_as_float(__float_as_int(x) ^ sm);
}
__device__ __forceinline__ v2f vsplat(float a) { v2f r; r.x = a; r.y = a; return r; }
__device__ __forceinline__ v2f vperp(v2f v) { v2f r; r.x = -v.y; r.y = v.x; return r; }  //  i*v
__device__ __forceinline__ v2f vperc(v2f v) { v2f r; r.x = v.y; r.y = -v.x; return r; }  // -i*v
__device__ __forceinline__ v2f vfma2(float a, v2f b, v2f c) {
  return __builtin_elementwise_fma(vsplat(a), b, c);
}
__device__ __forceinline__ v2f vmul2(float a, v2f b) { return vsplat(a) * b; }

// Closed-form row0 of U = RZ(a4)RY(a3)RZ(a2)RY(a1)RZ(a0)·H  (verified r8).
__device__ __forceinline__ void build_gate(float a0, float a1, float a2, float a3, float a4,
                                           float &w0r, float &w0i, float &w1r, float &w1i) {
  float sBp, cBp, sBm, cBm, sC, cC, sP, cP, sM, cM;
  __sincosf(0.5f * (a1 + a3), &sBp, &cBp);
  __sincosf(0.5f * (a1 - a3), &sBm, &cBm);
  __sincosf(0.5f * a2,        &sC,  &cC);
  __sincosf(0.5f * (a0 + a4), &sP,  &cP);
  __sincosf(0.5f * (a0 - a4), &sM,  &cM);
  float m00r =  cBp * cC, m00i = -cBm * sC;
  float m01r = -sBp * cC, m01i =  sBm * sC;
  float alr = fmaf(m00r, cP,  m00i * sP);
  float ali = fmaf(m00i, cP, -m00r * sP);
  float ber = fmaf(m01r, cM, -m01i * sM);
  float bei = fmaf(m01i, cM,  m01r * sM);
  w0r = RS2f * (alr + ber); w0i = RS2f * (ali + bei);
  w1r = RS2f * (alr - ber); w1i = RS2f * (ali - bei);
}

#define PICK_FULL                                                            \
  a0 = l0 ? P[0][0] : l1 ? P[1][1] : l2 ? P[2][2] : P[3][3];                 \
  a1 = l0 ? P[0][1] : l1 ? P[1][2] : l2 ? P[2][3] : 0.f;                     \
  a2 = l0 ? P[0][2] : l1 ? P[1][3] : l2 ? P[3][0] : 0.f;                     \
  a3 = l0 ? P[0][3] : l1 ? P[2][0] : l2 ? P[3][1] : 0.f;                     \
  a4 = l0 ? P[1][0] : l1 ? P[2][1] : l2 ? P[3][2] : 0.f;

#define PICK_W2                                                              \
  a0 = l0 ? P[0][0] : l1 ? P[2][1] : 0.f;                                    \
  a1 = l0 ? P[0][1] : l1 ? P[3][0] : 0.f;                                    \
  a2 = l0 ? P[1][0] : l1 ? P[3][1] : 0.f;                                    \
  a3 = l0 ? P[1][1] : 0.f;                                                   \
  a4 = l0 ? P[2][0] : 0.f;

#define PICK_H2                                                              \
  a0 = l0 ? P[0][0] : l1 ? P[1][1] : 0.f;                                    \
  a1 = l0 ? P[0][1] : l1 ? P[1][2] : 0.f;                                    \
  a2 = l0 ? P[0][2] : l1 ? P[1][3] : 0.f;                                    \
  a3 = l0 ? P[0][3] : 0.f;                                                   \
  a4 = l0 ? P[1][0] : 0.f;

#define PICK_22                                                              \
  a0 = l0 ? P[0][0] : 0.f;                                                   \
  a1 = l0 ? P[0][1] : 0.f;                                                   \
  a2 = l0 ? P[1][0] : 0.f;                                                   \
  a3 = l0 ? P[1][1] : 0.f;                                                   \
  a4 = 0.f;

// Apply gate (Wc) to state + CRZ + Ry + Z expectations; emits PRE-butterfly
// per-lane o-values into np0..np3. Verified r8 math, readout split off (r10).
#define APPLY_Z do {                                                         \
  { float w0r = dppf<QP_BC0>(Wc0), w0i = dppf<QP_BC0>(Wc1);                  \
    float w1r = dppf<QP_BC0>(Wc2), w1i = dppf<QP_BC0>(Wc3);                  \
    float uar = sxor(w0r, sm0), uai = w0i;                                   \
    float ubr = w1r,            ubi = sxor(w1i, sm0);                        \
    _Pragma("unroll")                                                        \
    for (int k = 0; k < 4; ++k) {                                            \
      v2f p = dpp2<QP_XOR2>(s[k]);                                           \
      v2f a = s[k];                                                          \
      s[k] = vfma2(uar, a, vfma2(uai, vperp(a),                              \
                   vfma2(ubr, p, vmul2(ubi, vperp(p)))));                    \
    } }                                                                      \
  { float w0r = dppf<QP_BC1>(Wc0), w0i = dppf<QP_BC1>(Wc1);                  \
    float w1r = dppf<QP_BC1>(Wc2), w1i = dppf<QP_BC1>(Wc3);                  \
    float uar = sxor(w0r, sm1), uai = w0i;                                   \
    float ubr = w1r,            ubi = sxor(w1i, sm1);                        \
    _Pragma("unroll")                                                        \
    for (int k = 0; k < 4; ++k) {                                            \
      v2f p = dpp2<QP_XOR1>(s[k]);                                           \
      v2f a = s[k];                                                          \
      s[k] = vfma2(uar, a, vfma2(uai, vperp(a),                              \
                   vfma2(ubr, p, vmul2(ubi, vperp(p)))));                    \
    } }                                                                      \
  { float w0r = dppf<QP_BC2>(Wc0), w0i = dppf<QP_BC2>(Wc1);                  \
    float w1r = dppf<QP_BC2>(Wc2), w1i = dppf<QP_BC2>(Wc3);                  \
    float nw0r = -w0r, nw0i = -w0i;                                          \
    _Pragma("unroll")                                                        \
    for (int k = 0; k < 2; ++k) {                                            \
      v2f lo = s[k], hi = s[k+2];                                            \
      s[k]   = vfma2(w0r, lo, vfma2(w0i, vperp(lo),                          \
                     vfma2(w1r, hi, vmul2(w1i, vperp(hi)))));                \
      s[k+2] = vfma2(w1r, lo, vfma2(w1i, vperc(lo),                          \
                     vfma2(nw0r, hi, vmul2(nw0i, vperc(hi)))));              \
    } }                                                                      \
  { float w0r = dppf<QP_BC3>(Wc0), w0i = dppf<QP_BC3>(Wc1);                  \
    float w1r = dppf<QP_BC3>(Wc2), w1i = dppf<QP_BC3>(Wc3);                  \
    float nw0r = -w0r, nw0i = -w0i;                                          \
    _Pragma("unroll")                                                        \
    for (int k = 0; k < 4; k += 2) {                                         \
      v2f lo = s[k], hi = s[k+1];                                            \
      s[k]   = vfma2(w0r, lo, vfma2(w0i, vperp(lo),                          \
                     vfma2(w1r, hi, vmul2(w1i, vperp(hi)))));                \
      s[k+1] = vfma2(w1r, lo, vfma2(w1i, vperc(lo),                          \
                     vfma2(nw0r, hi, vmul2(nw0i, vperc(hi)))));              \
    } }                                                                      \
  _Pragma("unroll")                                                          \
  for (int k = 0; k < 4; ++k)                                                \
    s[k] = vfma2(czk[k], s[k], vmul2(szk[k], vperp(s[k])));                  \
  _Pragma("unroll")                                                          \
  for (int k = 0; k < 4; ++k) {                                              \
    v2f p = dpp2<QP_XOR2>(s[k]);                                             \
    s[k] = vfma2(cry, s[k], vmul2(sgn0, p));                                 \
  }                                                                          \
  _Pragma("unroll")                                                          \
  for (int k = 0; k < 4; ++k) {                                              \
    v2f p = dpp2<QP_XOR1>(s[k]);                                             \
    s[k] = vfma2(cry, s[k], vmul2(sgn1, p));                                 \
  }                                                                          \
  _Pragma("unroll")                                                          \
  for (int k = 0; k < 2; ++k) {                                              \
    v2f lo = s[k], hi = s[k+2];                                              \
    s[k]   = vfma2(cry, lo, vmul2(nsry, hi));                                \
    s[k+2] = vfma2(sry, lo, vmul2(cry, hi));                                 \
  }                                                                          \
  _Pragma("unroll")                                                          \
  for (int k = 0; k < 4; k += 2) {                                           \
    v2f lo = s[k], hi = s[k+1];                                              \
    s[k]   = vfma2(cry, lo, vmul2(nsry, hi));                                \
    s[k+1] = vfma2(sry, lo, vmul2(cry, hi));                                 \
  }                                                                          \
  { v2f q0 = s[0]*s[0], q1 = s[1]*s[1], q2 = s[2]*s[2], q3 = s[3]*s[3];      \
    float p0 = q0.x + q0.y, p1 = q1.x + q1.y;                                \
    float p2 = q2.x + q2.y, p3 = q3.x + q3.y;                                \
    float s01 = p0 + p1, s23 = p2 + p3;                                      \
    float t_  = s01 + s23;                                                   \
    np0 = sxor(t_, sm0);                                                     \
    np1 = sxor(t_, sm1);                                                     \
    np2 = s01 - s23;                                                         \
    np3 = (p0 - p1) + (p2 - p3);                                             \
  }                                                                          \
} while (0)

// Deferred readout: butterfly + fc1 fold for the PENDING window (pd*, pdWin).
#define BF_FOLD do {                                                         \
  float o0 = pd0, o1 = pd1, o2 = pd2, o3 = pd3;                              \
  o0 += dppf<QP_XOR1>(o0); o0 += dppf<QP_XOR2>(o0);                          \
  o1 += dppf<QP_XOR1>(o1); o1 += dppf<QP_XOR2>(o1);                          \
  o2 += dppf<QP_XOR1>(o2); o2 += dppf<QP_XOR2>(o2);                          \
  o3 += dppf<QP_XOR1>(o3); o3 += dppf<QP_XOR2>(o3);                          \
  const float* wp = swl + pdWin * 4;                                         \
  float4 wv0 = *(const float4*)(wp);                                         \
  float4 wv1 = *(const float4*)(wp + 784);                                   \
  float4 wv2 = *(const float4*)(wp + 1568);                                  \
  float4 wv3 = *(const float4*)(wp + 2352);                                  \
  float4 wv4 = *(const float4*)(wp + 3136);                                  \
  h1[0] = fmaf(wv0.x, o0, fmaf(wv0.y, o1, fmaf(wv0.z, o2, fmaf(wv0.w, o3, h1[0])))); \
  h1[1] = fmaf(wv1.x, o0, fmaf(wv1.y, o1, fmaf(wv1.z, o2, fmaf(wv1.w, o3, h1[1])))); \
  h1[2] = fmaf(wv2.x, o0, fmaf(wv2.y, o1, fmaf(wv2.z, o2, fmaf(wv2.w, o3, h1[2])))); \
  h1[3] = fmaf(wv3.x, o0, fmaf(wv3.y, o1, fmaf(wv3.z, o2, fmaf(wv3.w, o3, h1[3])))); \
  h1[4] = fmaf(wv4.x, o0, fmaf(wv4.y, o1, fmaf(wv4.z, o2, fmaf(wv4.w, o3, h1[4])))); \
} while (0)

#define SHIFT_PEND(WIN)  pd0 = np0; pd1 = np1; pd2 = np2; pd3 = np3; pdWin = (WIN);
#define ROTATE_W  Wc0 = Wn0; Wc1 = Wn1; Wc2 = Wn2; Wc3 = Wn3;

__global__ void __launch_bounds__(256)
quanv_kernel(const float* __restrict__ x,
             const float* __restrict__ crz_t,
             const float* __restrict__ ry_t,
             const float* __restrict__ fc1_w,
             const float* __restrict__ fc1_b,
             const float* __restrict__ fc2_w,
             const float* __restrict__ fc2_b,
             float* __restrict__ out, int B)
{
  __shared__ float sw[20 * 784];
  const int tid = threadIdx.x;
  for (int i = tid; i < (20 * 784) / 4; i += 256)
    ((float4*)sw)[i] = ((const float4*)fc1_w)[i];
  __syncthreads();

  const int l = tid & 3;                       // lane within 4-lane group
  const int b = (blockIdx.x * 256 + tid) >> 2; // element id
  if (b >= B) return;
  const float* img = x + (size_t)b * 784;
  const bool l0 = (l == 0), l1 = (l == 1), l2 = (l == 2);

  // ---- uniform scalar-derived constants ----
  const float theta = crz_t[0];
  const float ryt   = ry_t[0];
  float cry, sry;
  __sincosf(0.5f * ryt, &sry, &cry);
  const float nsry = -sry;
  const float sgn0 = (l & 2) ? sry : -sry;
  const float sgn1 = (l & 1) ? sry : -sry;
  const int sm0 = (l & 2) ? (int)0x80000000 : 0;
  const int sm1 = (l & 1) ? (int)0x80000000 : 0;

  float g0,g1,g2,g3;
  if      (l == 0) { g0= 0.f; g1=-1.f; g2=-1.f; g3=0.f; }
  else if (l == 1) { g0=-1.f; g1=-2.f; g2= 0.f; g3=1.f; }
  else if (l == 2) { g0=-1.f; g1= 0.f; g2=-2.f; g3=1.f; }
  else             { g0= 0.f; g1= 1.f; g2= 1.f; g3=4.f; }
  float czk[4], szk[4];
  __sincosf(0.5f*theta*g0, &szk[0], &czk[0]);
  __sincosf(0.5f*theta*g1, &szk[1], &czk[1]);
  __sincosf(0.5f*theta*g2, &szk[2], &czk[2]);
  __sincosf(0.5f*theta*g3, &szk[3], &czk[3]);

  // state: amp n = 4*l + k; s[k] = (re, im) packed
  v2f s[4];
#pragma unroll
  for (int k = 0; k < 4; ++k) { s[k].x = 0.f; s[k].y = 0.f; }
  if (l == 0) s[0].x = 1.f;

  float h1[5];
#pragma unroll
  for (int j = 0; j < 5; ++j) h1[j] = 0.f;
  const float* swl = sw + 5 * l * 784;

  float P[4][4];
  float a0, a1, a2, a3, a4;
  float Wc0, Wc1, Wc2, Wc3, Wn0, Wn1, Wn2, Wn3;
  float np0, np1, np2, np3;
  float pd0 = 0.f, pd1 = 0.f, pd2 = 0.f, pd3 = 0.f;  // pending readout (0-seeded)
  int pdWin = 0;

  // ================= main rows: wi = 0..12 (h = 4 always) =================
#pragma unroll 1
  for (int wi = 0; wi < 13; ++wi) {
    const float* imgw = img + (2 * wi) * 28;

    // peel wj = 0: fresh load + build only (prev row's pending carries over)
#pragma unroll
    for (int r = 0; r < 4; ++r) {
      float4 v = *(const float4*)(imgw + r * 28);
      P[r][0]=v.x; P[r][1]=v.y; P[r][2]=v.z; P[r][3]=v.w;
    }
    PICK_FULL;
    build_gate(a0, a1, a2, a3, a4, Wc0, Wc1, Wc2, Wc3);

    // prefetch window 1's new columns (cols 4,5)
    float2 Q0 = *(const float2*)(imgw + 0 * 28 + 4);
    float2 Q1 = *(const float2*)(imgw + 1 * 28 + 4);
    float2 Q2 = *(const float2*)(imgw + 2 * 28 + 4);
    float2 Q3 = *(const float2*)(imgw + 3 * 28 + 4);

    // hot loop: wj = 1..12 — branch-free; unroll 4; slide uses prefetched Q,
    // next iteration's Q loads issue here (load-to-use = one full window).
    // Body: build(wj) || apply(wj-1) || deferred butterfly+fold(wj-2).
#pragma unroll 4
    for (int wj = 1; wj <= 12; ++wj) {
      P[0][0]=P[0][2]; P[0][1]=P[0][3]; P[0][2]=Q0.x; P[0][3]=Q0.y;
      P[1][0]=P[1][2]; P[1][1]=P[1][3]; P[1][2]=Q1.x; P[1][3]=Q1.y;
      P[2][0]=P[2][2]; P[2][1]=P[2][3]; P[2][2]=Q2.x; P[2][3]=Q2.y;
      P[3][0]=P[3][2]; P[3][1]=P[3][3]; P[3][2]=Q3.x; P[3][3]=Q3.y;
      const int c0n = (wj < 12) ? (2 * wj + 4) : 24;   // clamped: last prefetch unused
      Q0 = *(const float2*)(imgw + 0 * 28 + c0n);
      Q1 = *(const float2*)(imgw + 1 * 28 + c0n);
      Q2 = *(const float2*)(imgw + 2 * 28 + c0n);
      Q3 = *(const float2*)(imgw + 3 * 28 + c0n);
      PICK_FULL;
      build_gate(a0, a1, a2, a3, a4, Wn0, Wn1, Wn2, Wn3);
      APPLY_Z;                                   // window wj-1 -> np
      BF_FOLD;                                   // window wj-2 (or older)
      SHIFT_PEND(wi * 14 + wj - 1);
      ROTATE_W;
    }

    // peel wj = 13: zero-fill slide
#pragma unroll
    for (int r = 0; r < 4; ++r) {
      P[r][0] = P[r][2]; P[r][1] = P[r][3]; P[r][2] = 0.f; P[r][3] = 0.f;
    }
    PICK_W2;
    build_gate(a0, a1, a2, a3, a4, Wn0, Wn1, Wn2, Wn3);
    APPLY_Z;                                     // window 12
    BF_FOLD;                                     // window 11
    SHIFT_PEND(wi * 14 + 12);
    ROTATE_W;
    APPLY_Z;                                     // window 13
    BF_FOLD;                                     // window 12
    SHIFT_PEND(wi * 14 + 13);
  }

  // ================= tail row: wi = 13 (h = 2) =================
  {
    const float* imgw = img + 26 * 28;
#pragma unroll
    for (int r = 0; r < 2; ++r) {
      float4 v = *(const float4*)(imgw + r * 28);
      P[r][0]=v.x; P[r][1]=v.y; P[r][2]=v.z; P[r][3]=v.w;
    }
#pragma unroll
    for (int r = 2; r < 4; ++r) { P[r][0]=0.f; P[r][1]=0.f; P[r][2]=0.f; P[r][3]=0.f; }
    PICK_H2;
    build_gate(a0, a1, a2, a3, a4, Wc0, Wc1, Wc2, Wc3);

    float2 Q0 = *(const float2*)(imgw + 4);
    float2 Q1 = *(const float2*)(imgw + 28 + 4);

#pragma unroll 4
    for (int wj = 1; wj <= 12; ++wj) {
      P[0][0]=P[0][2]; P[0][1]=P[0][3]; P[0][2]=Q0.x; P[0][3]=Q0.y;
      P[1][0]=P[1][2]; P[1][1]=P[1][3]; P[1][2]=Q1.x; P[1][3]=Q1.y;
      const int c0n = (wj < 12) ? (2 * wj + 4) : 24;
      Q0 = *(const float2*)(imgw + c0n);
      Q1 = *(const float2*)(imgw + 28 + c0n);
      PICK_H2;
      build_gate(a0, a1, a2, a3, a4, Wn0, Wn1, Wn2, Wn3);
      APPLY_Z;
      BF_FOLD;
      SHIFT_PEND(182 + wj - 1);
      ROTATE_W;
    }

    P[0][0]=P[0][2]; P[0][1]=P[0][3]; P[0][2]=0.f; P[0][3]=0.f;
    P[1][0]=P[1][2]; P[1][1]=P[1][3]; P[1][2]=0.f; P[1][3]=0.f;
    PICK_22;
    build_gate(a0, a1, a2, a3, a4, Wn0, Wn1, Wn2, Wn3);
    APPLY_Z;                                     // window 194
    BF_FOLD;                                     // window 193
    SHIFT_PEND(182 + 12);
    ROTATE_W;
    APPLY_Z;                                     // window 195
    BF_FOLD;                                     // window 194
    SHIFT_PEND(182 + 13);
  }

  // drain the pipeline: fold window 195
  BF_FOLD;

  // ---- epilogue: bias + leaky relu + fc2, reduce over group ----
  float pa = 0.f, pb = 0.f;
#pragma unroll
  for (int j = 0; j < 5; ++j) {
    const int r = 5 * l + j;
    float v = h1[j] + fc1_b[r];
    v = (v > 0.f) ? v : 0.1f * v;
    pa = fmaf(fc2_w[r],      v, pa);
    pb = fmaf(fc2_w[20 + r], v, pb);
  }
  pa += dppf<QP_XOR1>(pa); pa += dppf<QP_XOR2>(pa);
  pb += dppf<QP_XOR1>(pb); pb += dppf<QP_XOR2>(pb);
  if (l == 0) {
    float2 res; res.x = pa + fc2_b[0]; res.y = pb + fc2_b[1];
    *(float2*)(out + (size_t)b * 2) = res;
  }
}

extern "C" void kernel_launch(void* const* d_in, const int* in_sizes, int n_in,
                              void* d_out, int out_size, void* d_ws, size_t ws_size,
                              hipStream_t stream) {
  const float* x      = (const float*)d_in[0];
  const float* crz_t  = (const float*)d_in[1];
  const float* ry_t   = (const float*)d_in[2];
  const float* fc1_w  = (const float*)d_in[3];
  const float* fc1_b  = (const float*)d_in[4];
  const float* fc2_w  = (const float*)d_in[5];
  const float* fc2_b  = (const float*)d_in[6];
  float* out = (float*)d_out;
  const int B = in_sizes[0] / 784;
  const int grid = (B * 4 + 255) / 256;
  quanv_kernel<<<grid, 256, 0, stream>>>(x, crz_t, ry_t, fc1_w, fc1_b,
                                         fc2_w, fc2_b, out, B);
}

// Round 12
// 223.483 us; speedup vs baseline: 1.1799x; 1.0074x over previous
//
#include <hip/hip_runtime.h>

#define RS2f 0.70710678118654752f

// DPP quad_perm encodings: sel0 | sel1<<2 | sel2<<4 | sel3<<6
#define QP_XOR1 0xB1   // [1,0,3,2]
#define QP_XOR2 0x4E   // [2,3,0,1]
#define QP_BC0  0x00
#define QP_BC1  0x55
#define QP_BC2  0xAA
#define QP_BC3  0xFF

typedef float v2f __attribute__((ext_vector_type(2)));

template<int CTRL> __device__ __forceinline__ float dppf(float x) {
  return __int_as_float(__builtin_amdgcn_update_dpp(
      0, __float_as_int(x), CTRL, 0xF, 0xF, true));
}
template<int CTRL> __device__ __forceinline__ v2f dpp2(v2f v) {
  v2f r; r.x = dppf<CTRL>(v.x); r.y = dppf<CTRL>(v.y); return r;
}

__device__ __forceinline__ float sxor(float x, int sm) {
  return __int_as_float(__float_as_int(x) ^ sm);
}
__device__ __forceinline__ v2f vsplat(float a) { v2f r; r.x = a; r.y = a; return r; }
__device__ __forceinline__ v2f vperp(v2f v) { v2f r; r.x = -v.y; r.y = v.x; return r; }  //  i*v
__device__ __forceinline__ v2f vperc(v2f v) { v2f r; r.x = v.y; r.y = -v.x; return r; }  // -i*v
__device__ __forceinline__ v2f vfma2(float a, v2f b, v2f c) {
  return __builtin_elementwise_fma(vsplat(a), b, c);
}
__device__ __forceinline__ v2f vfma2v(v2f a, v2f b, v2f c) {
  return __builtin_elementwise_fma(a, b, c);
}
__device__ __forceinline__ v2f vmul2(float a, v2f b) { return vsplat(a) * b; }

// Closed-form row0 of G = RZ(a4)RY(a3)RZ(a2)RY(a1)RZ(a0) · [[u,v],[v,-u]].
// The right factor is H (u=v=rs2) or H·Ry(t) (u=rs2(c+s), v=rs2(c-s)) — both
// real symmetric det=-1, so row1 = (conj(w1), -conj(w0)) holds in either case
// and the APPLY code is unchanged (r12 Ry-absorption).
__device__ __forceinline__ void build_gate(float a0, float a1, float a2, float a3, float a4,
                                           float u, float v,
                                           float &w0r, float &w0i, float &w1r, float &w1i) {
  float sBp, cBp, sBm, cBm, sC, cC, sP, cP, sM, cM;
  __sincosf(0.5f * (a1 + a3), &sBp, &cBp);
  __sincosf(0.5f * (a1 - a3), &sBm, &cBm);
  __sincosf(0.5f * a2,        &sC,  &cC);
  __sincosf(0.5f * (a0 + a4), &sP,  &cP);
  __sincosf(0.5f * (a0 - a4), &sM,  &cM);
  float m00r =  cBp * cC, m00i = -cBm * sC;
  float m01r = -sBp * cC, m01i =  sBm * sC;
  float alr = fmaf(m00r, cP,  m00i * sP);
  float ali = fmaf(m00i, cP, -m00r * sP);
  float ber = fmaf(m01r, cM, -m01i * sM);
  float bei = fmaf(m01i, cM,  m01r * sM);
  w0r = fmaf(u, alr, v * ber); w0i = fmaf(u, ali, v * bei);
  w1r = fmaf(v, alr, -u * ber); w1i = fmaf(v, ali, -u * bei);
}

#define PICK_FULL                                                            \
  a0 = l0 ? P[0][0] : l1 ? P[1][1] : l2 ? P[2][2] : P[3][3];                 \
  a1 = l0 ? P[0][1] : l1 ? P[1][2] : l2 ? P[2][3] : 0.f;                     \
  a2 = l0 ? P[0][2] : l1 ? P[1][3] : l2 ? P[3][0] : 0.f;                     \
  a3 = l0 ? P[0][3] : l1 ? P[2][0] : l2 ? P[3][1] : 0.f;                     \
  a4 = l0 ? P[1][0] : l1 ? P[2][1] : l2 ? P[3][2] : 0.f;

#define PICK_W2                                                              \
  a0 = l0 ? P[0][0] : l1 ? P[2][1] : 0.f;                                    \
  a1 = l0 ? P[0][1] : l1 ? P[3][0] : 0.f;                                    \
  a2 = l0 ? P[1][0] : l1 ? P[3][1] : 0.f;                                    \
  a3 = l0 ? P[1][1] : 0.f;                                                   \
  a4 = l0 ? P[2][0] : 0.f;

#define PICK_H2                                                              \
  a0 = l0 ? P[0][0] : l1 ? P[1][1] : 0.f;                                    \
  a1 = l0 ? P[0][1] : l1 ? P[1][2] : 0.f;                                    \
  a2 = l0 ? P[0][2] : l1 ? P[1][3] : 0.f;                                    \
  a3 = l0 ? P[0][3] : 0.f;                                                   \
  a4 = l0 ? P[1][0] : 0.f;

#define PICK_22                                                              \
  a0 = l0 ? P[0][0] : 0.f;                                                   \
  a1 = l0 ? P[0][1] : 0.f;                                                   \
  a2 = l0 ? P[1][0] : 0.f;                                                   \
  a3 = l0 ? P[1][1] : 0.f;                                                   \
  a4 = 0.f;

// Apply gate (Wc) + CRZ; readout via rotated observables on the post-CRZ
// state (Ry folded into next gate): o_w = ct*<Z_w> - st*<X_w>. Emits
// pre-butterfly per-lane o-partials into np0..np3. State chain is only
// wire0->wire1->wire2->wire3->CRZ; readout is off-chain.
#define APPLY_Z do {                                                         \
  { float w0r = dppf<QP_BC0>(Wc0), w0i = dppf<QP_BC0>(Wc1);                  \
    float w1r = dppf<QP_BC0>(Wc2), w1i = dppf<QP_BC0>(Wc3);                  \
    float uar = sxor(w0r, sm0), uai = w0i;                                   \
    float ubr = w1r,            ubi = sxor(w1i, sm0);                        \
    _Pragma("unroll")                                                        \
    for (int k = 0; k < 4; ++k) {                                            \
      v2f p = dpp2<QP_XOR2>(s[k]);                                           \
      v2f a = s[k];                                                          \
      s[k] = vfma2(uar, a, vfma2(uai, vperp(a),                              \
                   vfma2(ubr, p, vmul2(ubi, vperp(p)))));                    \
    } }                                                                      \
  { float w0r = dppf<QP_BC1>(Wc0), w0i = dppf<QP_BC1>(Wc1);                  \
    float w1r = dppf<QP_BC1>(Wc2), w1i = dppf<QP_BC1>(Wc3);                  \
    float uar = sxor(w0r, sm1), uai = w0i;                                   \
    float ubr = w1r,            ubi = sxor(w1i, sm1);                        \
    _Pragma("unroll")                                                        \
    for (int k = 0; k < 4; ++k) {                                            \
      v2f p = dpp2<QP_XOR1>(s[k]);                                           \
      v2f a = s[k];                                                          \
      s[k] = vfma2(uar, a, vfma2(uai, vperp(a),                              \
                   vfma2(ubr, p, vmul2(ubi, vperp(p)))));                    \
    } }                                                                      \
  { float w0r = dppf<QP_BC2>(Wc0), w0i = dppf<QP_BC2>(Wc1);                  \
    float w1r = dppf<QP_BC2>(Wc2), w1i = dppf<QP_BC2>(Wc3);                  \
    float nw0r = -w0r, nw0i = -w0i;                                          \
    _Pragma("unroll")                                                        \
    for (int k = 0; k < 2; ++k) {                                            \
      v2f lo = s[k], hi = s[k+2];                                            \
      s[k]   = vfma2(w0r, lo, vfma2(w0i, vperp(lo),                          \
                     vfma2(w1r, hi, vmul2(w1i, vperp(hi)))));                \
      s[k+2] = vfma2(w1r, lo, vfma2(w1i, vperc(lo),                          \
                     vfma2(nw0r, hi, vmul2(nw0i, vperc(hi)))));              \
    } }                                                                      \
  { float w0r = dppf<QP_BC3>(Wc0), w0i = dppf<QP_BC3>(Wc1);                  \
    float w1r = dppf<QP_BC3>(Wc2), w1i = dppf<QP_BC3>(Wc3);                  \
    float nw0r = -w0r, nw0i = -w0i;                                          \
    _Pragma("unroll")                                                        \
    for (int k = 0; k < 4; k += 2) {                                         \
      v2f lo = s[k], hi = s[k+1];                                            \
      s[k]   = vfma2(w0r, lo, vfma2(w0i, vperp(lo),                          \
                     vfma2(w1r, hi, vmul2(w1i, vperp(hi)))));                \
      s[k+1] = vfma2(w1r, lo, vfma2(w1i, vperc(lo),                          \
                     vfma2(nw0r, hi, vmul2(nw0i, vperc(hi)))));              \
    } }                                                                      \
  _Pragma("unroll")                                                          \
  for (int k = 0; k < 4; ++k)                                                \
    s[k] = vfma2(czk[k], s[k], vmul2(szk[k], vperp(s[k])));                  \
  /* readout: Z partials + X partials + rotate-observable combine */         \
  { v2f q0 = s[0]*s[0], q1 = s[1]*s[1], q2 = s[2]*s[2], q3 = s[3]*s[3];      \
    float p0 = q0.x + q0.y, p1 = q1.x + q1.y;                                \
    float p2 = q2.x + q2.y, p3 = q3.x + q3.y;                                \
    float s01 = p0 + p1, s23 = p2 + p3;                                      \
    float t_  = s01 + s23;                                                   \
    v2f xa0 = s[0] * dpp2<QP_XOR2>(s[0]);                                    \
    xa0 = vfma2v(s[1], dpp2<QP_XOR2>(s[1]), xa0);                            \
    xa0 = vfma2v(s[2], dpp2<QP_XOR2>(s[2]), xa0);                            \
    xa0 = vfma2v(s[3], dpp2<QP_XOR2>(s[3]), xa0);                            \
    v2f xa1 = s[0] * dpp2<QP_XOR1>(s[0]);                                    \
    xa1 = vfma2v(s[1], dpp2<QP_XOR1>(s[1]), xa1);                            \
    xa1 = vfma2v(s[2], dpp2<QP_XOR1>(s[2]), xa1);                            \
    xa1 = vfma2v(s[3], dpp2<QP_XOR1>(s[3]), xa1);                            \
    v2f xa2 = s[0] * s[2];  xa2 = vfma2v(s[1], s[3], xa2);                   \
    v2f xa3 = s[0] * s[1];  xa3 = vfma2v(s[2], s[3], xa3);                   \
    float x0 = xa0.x + xa0.y, x1 = xa1.x + xa1.y;                            \
    float x2 = xa2.x + xa2.y, x3 = xa3.x + xa3.y;                            \
    np0 = fmaf(ct, sxor(t_, sm0), -st  * x0);                                \
    np1 = fmaf(ct, sxor(t_, sm1), -st  * x1);                                \
    np2 = fmaf(ct, s01 - s23,     -st2 * x2);                                \
    np3 = fmaf(ct, (p0 - p1) + (p2 - p3), -st2 * x3);                        \
  }                                                                          \
} while (0)

// Deferred readout: butterfly + fc1 fold for the PENDING window (pd*, pdWin).
#define BF_FOLD do {                                                         \
  float o0 = pd0, o1 = pd1, o2 = pd2, o3 = pd3;                              \
  o0 += dppf<QP_XOR1>(o0); o0 += dppf<QP_XOR2>(o0);                          \
  o1 += dppf<QP_XOR1>(o1); o1 += dppf<QP_XOR2>(o1);                          \
  o2 += dppf<QP_XOR1>(o2); o2 += dppf<QP_XOR2>(o2);                          \
  o3 += dppf<QP_XOR1>(o3); o3 += dppf<QP_XOR2>(o3);                          \
  const float* wp = swl + pdWin * 4;                                         \
  float4 wv0 = *(const float4*)(wp);                                         \
  float4 wv1 = *(const float4*)(wp + 784);                                   \
  float4 wv2 = *(const float4*)(wp + 1568);                                  \
  float4 wv3 = *(const float4*)(wp + 2352);                                  \
  float4 wv4 = *(const float4*)(wp + 3136);                                  \
  h1[0] = fmaf(wv0.x, o0, fmaf(wv0.y, o1, fmaf(wv0.z, o2, fmaf(wv0.w, o3, h1[0])))); \
  h1[1] = fmaf(wv1.x, o0, fmaf(wv1.y, o1, fmaf(wv1.z, o2, fmaf(wv1.w, o3, h1[1])))); \
  h1[2] = fmaf(wv2.x, o0, fmaf(wv2.y, o1, fmaf(wv2.z, o2, fmaf(wv2.w, o3, h1[2])))); \
  h1[3] = fmaf(wv3.x, o0, fmaf(wv3.y, o1, fmaf(wv3.z, o2, fmaf(wv3.w, o3, h1[3])))); \
  h1[4] = fmaf(wv4.x, o0, fmaf(wv4.y, o1, fmaf(wv4.z, o2, fmaf(wv4.w, o3, h1[4])))); \
} while (0)

#define SHIFT_PEND(WIN)  pd0 = np0; pd1 = np1; pd2 = np2; pd3 = np3; pdWin = (WIN);
#define ROTATE_W  Wc0 = Wn0; Wc1 = Wn1; Wc2 = Wn2; Wc3 = Wn3;

__global__ void __launch_bounds__(256)
quanv_kernel(const float* __restrict__ x,
             const float* __restrict__ crz_t,
             const float* __restrict__ ry_t,
             const float* __restrict__ fc1_w,
             const float* __restrict__ fc1_b,
             const float* __restrict__ fc2_w,
             const float* __restrict__ fc2_b,
             float* __restrict__ out, int B)
{
  __shared__ float sw[20 * 784];
  const int tid = threadIdx.x;
  for (int i = tid; i < (20 * 784) / 4; i += 256)
    ((float4*)sw)[i] = ((const float4*)fc1_w)[i];
  __syncthreads();

  const int l = tid & 3;                       // lane within 4-lane group
  const int b = (blockIdx.x * 256 + tid) >> 2; // element id
  if (b >= B) return;
  const float* img = x + (size_t)b * 784;
  const bool l0 = (l == 0), l1 = (l == 1), l2 = (l == 2);

  // ---- uniform scalar-derived constants ----
  const float theta = crz_t[0];
  const float ryt   = ry_t[0];
  float cry, sry;
  __sincosf(0.5f * ryt, &sry, &cry);
  // H·Ry fold constants (windows >= 1); window 0 uses plain H (u=v=rs2)
  const float uH = RS2f * (cry + sry);
  const float vH = RS2f * (cry - sry);
  // rotated-observable constants: Ry† Z Ry = cos(t) Z - sin(t) X
  float st, ct;
  __sincosf(ryt, &st, &ct);
  const float st2 = 2.0f * st;                 // local wires: partials = X/2
  const int sm0 = (l & 2) ? (int)0x80000000 : 0;
  const int sm1 = (l & 1) ? (int)0x80000000 : 0;

  float g0,g1,g2,g3;
  if      (l == 0) { g0= 0.f; g1=-1.f; g2=-1.f; g3=0.f; }
  else if (l == 1) { g0=-1.f; g1=-2.f; g2= 0.f; g3=1.f; }
  else if (l == 2) { g0=-1.f; g1= 0.f; g2=-2.f; g3=1.f; }
  else             { g0= 0.f; g1= 1.f; g2= 1.f; g3=4.f; }
  float czk[4], szk[4];
  __sincosf(0.5f*theta*g0, &szk[0], &czk[0]);
  __sincosf(0.5f*theta*g1, &szk[1], &czk[1]);
  __sincosf(0.5f*theta*g2, &szk[2], &czk[2]);
  __sincosf(0.5f*theta*g3, &szk[3], &czk[3]);

  // state: amp n = 4*l + k; s[k] = (re, im) packed; carried PRE-Ry (post-CRZ)
  v2f s[4];
#pragma unroll
  for (int k = 0; k < 4; ++k) { s[k].x = 0.f; s[k].y = 0.f; }
  if (l == 0) s[0].x = 1.f;

  float h1[5];
#pragma unroll
  for (int j = 0; j < 5; ++j) h1[j] = 0.f;
  const float* swl = sw + 5 * l * 784;

  float P[4][4];
  float a0, a1, a2, a3, a4;
  float Wc0, Wc1, Wc2, Wc3, Wn0, Wn1, Wn2, Wn3;
  float np0, np1, np2, np3;
  float pd0 = 0.f, pd1 = 0.f, pd2 = 0.f, pd3 = 0.f;  // pending readout (0-seeded)
  int pdWin = 0;

  // ================= main rows: wi = 0..12 (h = 4 always) =================
#pragma unroll 1
  for (int wi = 0; wi < 13; ++wi) {
    const float* imgw = img + (2 * wi) * 28;
    // window (wi,0): plain H only at the very first window of the scan
    const float ug = (wi == 0) ? RS2f : uH;
    const float vg = (wi == 0) ? RS2f : vH;

    // peel wj = 0: fresh load + build only (prev row's pending carries over)
#pragma unroll
    for (int r = 0; r < 4; ++r) {
      float4 v = *(const float4*)(imgw + r * 28);
      P[r][0]=v.x; P[r][1]=v.y; P[r][2]=v.z; P[r][3]=v.w;
    }
    PICK_FULL;
    build_gate(a0, a1, a2, a3, a4, ug, vg, Wc0, Wc1, Wc2, Wc3);

    // prefetch window 1's new columns (cols 4,5)
    float2 Q0 = *(const float2*)(imgw + 0 * 28 + 4);
    float2 Q1 = *(const float2*)(imgw + 1 * 28 + 4);
    float2 Q2 = *(const float2*)(imgw + 2 * 28 + 4);
    float2 Q3 = *(const float2*)(imgw + 3 * 28 + 4);

    // hot loop: wj = 1..12 — branch-free; unroll 4.
    // Body: build(wj) || apply(wj-1) || deferred butterfly+fold(wj-2).
#pragma unroll 4
    for (int wj = 1; wj <= 12; ++wj) {
      P[0][0]=P[0][2]; P[0][1]=P[0][3]; P[0][2]=Q0.x; P[0][3]=Q0.y;
      P[1][0]=P[1][2]; P[1][1]=P[1][3]; P[1][2]=Q1.x; P[1][3]=Q1.y;
      P[2][0]=P[2][2]; P[2][1]=P[2][3]; P[2][2]=Q2.x; P[2][3]=Q2.y;
      P[3][0]=P[3][2]; P[3][1]=P[3][3]; P[3][2]=Q3.x; P[3][3]=Q3.y;
      const int c0n = (wj < 12) ? (2 * wj + 4) : 24;   // clamped: last prefetch unused
      Q0 = *(const float2*)(imgw + 0 * 28 + c0n);
      Q1 = *(const float2*)(imgw + 1 * 28 + c0n);
      Q2 = *(const float2*)(imgw + 2 * 28 + c0n);
      Q3 = *(const float2*)(imgw + 3 * 28 + c0n);
      PICK_FULL;
      build_gate(a0, a1, a2, a3, a4, uH, vH, Wn0, Wn1, Wn2, Wn3);
      APPLY_Z;                                   // window wj-1 -> np
      BF_FOLD;                                   // window wj-2 (or older)
      SHIFT_PEND(wi * 14 + wj - 1);
      ROTATE_W;
    }

    // peel wj = 13: zero-fill slide
#pragma unroll
    for (int r = 0; r < 4; ++r) {
      P[r][0] = P[r][2]; P[r][1] = P[r][3]; P[r][2] = 0.f; P[r][3] = 0.f;
    }
    PICK_W2;
    build_gate(a0, a1, a2, a3, a4, uH, vH, Wn0, Wn1, Wn2, Wn3);
    APPLY_Z;                                     // window 12
    BF_FOLD;                                     // window 11
    SHIFT_PEND(wi * 14 + 12);
    ROTATE_W;
    APPLY_Z;                                     // window 13
    BF_FOLD;                                     // window 12
    SHIFT_PEND(wi * 14 + 13);
  }

  // ================= tail row: wi = 13 (h = 2) =================
  {
    const float* imgw = img + 26 * 28;
#pragma unroll
    for (int r = 0; r < 2; ++r) {
      float4 v = *(const float4*)(imgw + r * 28);
      P[r][0]=v.x; P[r][1]=v.y; P[r][2]=v.z; P[r][3]=v.w;
    }
#pragma unroll
    for (int r = 2; r < 4; ++r) { P[r][0]=0.f; P[r][1]=0.f; P[r][2]=0.f; P[r][3]=0.f; }
    PICK_H2;
    build_gate(a0, a1, a2, a3, a4, uH, vH, Wc0, Wc1, Wc2, Wc3);

    float2 Q0 = *(const float2*)(imgw + 4);
    float2 Q1 = *(const float2*)(imgw + 28 + 4);

#pragma unroll 4
    for (int wj = 1; wj <= 12; ++wj) {
      P[0][0]=P[0][2]; P[0][1]=P[0][3]; P[0][2]=Q0.x; P[0][3]=Q0.y;
      P[1][0]=P[1][2]; P[1][1]=P[1][3]; P[1][2]=Q1.x; P[1][3]=Q1.y;
      const int c0n = (wj < 12) ? (2 * wj + 4) : 24;
      Q0 = *(const float2*)(imgw + c0n);
      Q1 = *(const float2*)(imgw + 28 + c0n);
      PICK_H2;
      build_gate(a0, a1, a2, a3, a4, uH, vH, Wn0, Wn1, Wn2, Wn3);
      APPLY_Z;
      BF_FOLD;
      SHIFT_PEND(182 + wj - 1);
      ROTATE_W;
    }

    P[0][0]=P[0][2]; P[0][1]=P[0][3]; P[0][2]=0.f; P[0][3]=0.f;
    P[1][0]=P[1][2]; P[1][1]=P[1][3]; P[1][2]=0.f; P[1][3]=0.f;
    PICK_22;
    build_gate(a0, a1, a2, a3, a4, uH, vH, Wn0, Wn1, Wn2, Wn3);
    APPLY_Z;                                     // window 194
    BF_FOLD;                                     // window 193
    SHIFT_PEND(182 + 12);
    ROTATE_W;
    APPLY_Z;                                     // window 195
    BF_FOLD;                                     // window 194
    SHIFT_PEND(182 + 13);
  }

  // drain the pipeline: fold window 195
  BF_FOLD;

  // ---- epilogue: bias + leaky relu + fc2, reduce over group ----
  float pa = 0.f, pb = 0.f;
#pragma unroll
  for (int j = 0; j < 5; ++j) {
    const int r = 5 * l + j;
    float v = h1[j] + fc1_b[r];
    v = (v > 0.f) ? v : 0.1f * v;
    pa = fmaf(fc2_w[r],      v, pa);
    pb = fmaf(fc2_w[20 + r], v, pb);
  }
  pa += dppf<QP_XOR1>(pa); pa += dppf<QP_XOR2>(pa);
  pb += dppf<QP_XOR1>(pb); pb += dppf<QP_XOR2>(pb);
  if (l == 0) {
    float2 res; res.x = pa + fc2_b[0]; res.y = pb + fc2_b[1];
    *(float2*)(out + (size_t)b * 2) = res;
  }
}

extern "C" void kernel_launch(void* const* d_in, const int* in_sizes, int n_in,
                              void* d_out, int out_size, void* d_ws, size_t ws_size,
                              hipStream_t stream) {
  const float* x      = (const float*)d_in[0];
  const float* crz_t  = (const float*)d_in[1];
  const float* ry_t   = (const float*)d_in[2];
  const float* fc1_w  = (const float*)d_in[3];
  const float* fc1_b  = (const float*)d_in[4];
  const float* fc2_w  = (const float*)d_in[5];
  const float* fc2_b  = (const float*)d_in[6];
  float* out = (float*)d_out;
  const int B = in_sizes[0] / 784;
  const int grid = (B * 4 + 255) / 256;
  quanv_kernel<<<grid, 256, 0, stream>>>(x, crz_t, ry_t, fc1_w, fc1_b,
                                         fc2_w, fc2_b, out, B);
}

// Round 13
// 222.941 us; speedup vs baseline: 1.1828x; 1.0024x over previous
//
#include <hip/hip_runtime.h>

#define RS2f 0.70710678118654752f

// DPP quad_perm encodings: sel0 | sel1<<2 | sel2<<4 | sel3<<6
#define QP_XOR1 0xB1   // [1,0,3,2]
#define QP_XOR2 0x4E   // [2,3,0,1]
#define QP_BC0  0x00
#define QP_BC1  0x55
#define QP_BC2  0xAA
#define QP_BC3  0xFF

typedef float v2f __attribute__((ext_vector_type(2)));

template<int CTRL> __device__ __forceinline__ float dppf(float x) {
  return __int_as_float(__builtin_amdgcn_update_dpp(
      0, __float_as_int(x), CTRL, 0xF, 0xF, true));
}
template<int CTRL> __device__ __forceinline__ v2f dpp2(v2f v) {
  v2f r; r.x = dppf<CTRL>(v.x); r.y = dppf<CTRL>(v.y); return r;
}

__device__ __forceinline__ float sxor(float x, int sm) {
  return __int_as_float(__float_as_int(x) ^ sm);
}
__device__ __forceinline__ v2f vsplat(float a) { v2f r; r.x = a; r.y = a; return r; }
__device__ __forceinline__ v2f vperp(v2f v) { v2f r; r.x = -v.y; r.y = v.x; return r; }  //  i*v
__device__ __forceinline__ v2f vperc(v2f v) { v2f r; r.x = v.y; r.y = -v.x; return r; }  // -i*v
__device__ __forceinline__ v2f vfma2(float a, v2f b, v2f c) {
  return __builtin_elementwise_fma(vsplat(a), b, c);
}
__device__ __forceinline__ v2f vmul2(float a, v2f b) { return vsplat(a) * b; }

// Closed-form row0 of U = RZ(a4)RY(a3)RZ(a2)RY(a1)RZ(a0)·H  (verified r8).
__device__ __forceinline__ void build_gate(float a0, float a1, float a2, float a3, float a4,
                                           float &w0r, float &w0i, float &w1r, float &w1i) {
  float sBp, cBp, sBm, cBm, sC, cC, sP, cP, sM, cM;
  __sincosf(0.5f * (a1 + a3), &sBp, &cBp);
  __sincosf(0.5f * (a1 - a3), &sBm, &cBm);
  __sincosf(0.5f * a2,        &sC,  &cC);
  __sincosf(0.5f * (a0 + a4), &sP,  &cP);
  __sincosf(0.5f * (a0 - a4), &sM,  &cM);
  float m00r =  cBp * cC, m00i = -cBm * sC;
  float m01r = -sBp * cC, m01i =  sBm * sC;
  float alr = fmaf(m00r, cP,  m00i * sP);
  float ali = fmaf(m00i, cP, -m00r * sP);
  float ber = fmaf(m01r, cM, -m01i * sM);
  float bei = fmaf(m01i, cM,  m01r * sM);
  w0r = RS2f * (alr + ber); w0i = RS2f * (ali + bei);
  w1r = RS2f * (alr - ber); w1i = RS2f * (ali - bei);
}

#define PICK_FULL                                                            \
  a0 = l0 ? P[0][0] : l1 ? P[1][1] : l2 ? P[2][2] : P[3][3];                 \
  a1 = l0 ? P[0][1] : l1 ? P[1][2] : l2 ? P[2][3] : 0.f;                     \
  a2 = l0 ? P[0][2] : l1 ? P[1][3] : l2 ? P[3][0] : 0.f;                     \
  a3 = l0 ? P[0][3] : l1 ? P[2][0] : l2 ? P[3][1] : 0.f;                     \
  a4 = l0 ? P[1][0] : l1 ? P[2][1] : l2 ? P[3][2] : 0.f;

#define PICK_W2                                                              \
  a0 = l0 ? P[0][0] : l1 ? P[2][1] : 0.f;                                    \
  a1 = l0 ? P[0][1] : l1 ? P[3][0] : 0.f;                                    \
  a2 = l0 ? P[1][0] : l1 ? P[3][1] : 0.f;                                    \
  a3 = l0 ? P[1][1] : 0.f;                                                   \
  a4 = l0 ? P[2][0] : 0.f;

#define PICK_H2                                                              \
  a0 = l0 ? P[0][0] : l1 ? P[1][1] : 0.f;                                    \
  a1 = l0 ? P[0][1] : l1 ? P[1][2] : 0.f;                                    \
  a2 = l0 ? P[0][2] : l1 ? P[1][3] : 0.f;                                    \
  a3 = l0 ? P[0][3] : 0.f;                                                   \
  a4 = l0 ? P[1][0] : 0.f;

#define PICK_22                                                              \
  a0 = l0 ? P[0][0] : 0.f;                                                   \
  a1 = l0 ? P[0][1] : 0.f;                                                   \
  a2 = l0 ? P[1][0] : 0.f;                                                   \
  a3 = l0 ? P[1][1] : 0.f;                                                   \
  a4 = 0.f;

// Apply gate (Wc) to state + CRZ + Ry + Z expectations; emits PRE-butterfly
// per-lane o-values into np0..np3. Verified r8 math, readout split off (r10).
#define APPLY_Z do {                                                         \
  { float w0r = dppf<QP_BC0>(Wc0), w0i = dppf<QP_BC0>(Wc1);                  \
    float w1r = dppf<QP_BC0>(Wc2), w1i = dppf<QP_BC0>(Wc3);                  \
    float uar = sxor(w0r, sm0), uai = w0i;                                   \
    float ubr = w1r,            ubi = sxor(w1i, sm0);                        \
    _Pragma("unroll")                                                        \
    for (int k = 0; k < 4; ++k) {                                            \
      v2f p = dpp2<QP_XOR2>(s[k]);                                           \
      v2f a = s[k];                                                          \
      s[k] = vfma2(uar, a, vfma2(uai, vperp(a),                              \
                   vfma2(ubr, p, vmul2(ubi, vperp(p)))));                    \
    } }                                                                      \
  { float w0r = dppf<QP_BC1>(Wc0), w0i = dppf<QP_BC1>(Wc1);                  \
    float w1r = dppf<QP_BC1>(Wc2), w1i = dppf<QP_BC1>(Wc3);                  \
    float uar = sxor(w0r, sm1), uai = w0i;                                   \
    float ubr = w1r,            ubi = sxor(w1i, sm1);                        \
    _Pragma("unroll")                                                        \
    for (int k = 0; k < 4; ++k) {                                            \
      v2f p = dpp2<QP_XOR1>(s[k]);                                           \
      v2f a = s[k];                                                          \
      s[k] = vfma2(uar, a, vfma2(uai, vperp(a),                              \
                   vfma2(ubr, p, vmul2(ubi, vperp(p)))));                    \
    } }                                                                      \
  { float w0r = dppf<QP_BC2>(Wc0), w0i = dppf<QP_BC2>(Wc1);                  \
    float w1r = dppf<QP_BC2>(Wc2), w1i = dppf<QP_BC2>(Wc3);                  \
    float nw0r = -w0r, nw0i = -w0i;                                          \
    _Pragma("unroll")                                                        \
    for (int k = 0; k < 2; ++k) {                                            \
      v2f lo = s[k], hi = s[k+2];                                            \
      s[k]   = vfma2(w0r, lo, vfma2(w0i, vperp(lo),                          \
                     vfma2(w1r, hi, vmul2(w1i, vperp(hi)))));                \
      s[k+2] = vfma2(w1r, lo, vfma2(w1i, vperc(lo),                          \
                     vfma2(nw0r, hi, vmul2(nw0i, vperc(hi)))));              \
    } }                                                                      \
  { float w0r = dppf<QP_BC3>(Wc0), w0i = dppf<QP_BC3>(Wc1);                  \
    float w1r = dppf<QP_BC3>(Wc2), w1i = dppf<QP_BC3>(Wc3);                  \
    float nw0r = -w0r, nw0i = -w0i;                                          \
    _Pragma("unroll")                                                        \
    for (int k = 0; k < 4; k += 2) {                                         \
      v2f lo = s[k], hi = s[k+1];                                            \
      s[k]   = vfma2(w0r, lo, vfma2(w0i, vperp(lo),                          \
                     vfma2(w1r, hi, vmul2(w1i, vperp(hi)))));                \
      s[k+1] = vfma2(w1r, lo, vfma2(w1i, vperc(lo),                          \
                     vfma2(nw0r, hi, vmul2(nw0i, vperc(hi)))));              \
    } }                                                                      \
  _Pragma("unroll")                                                          \
  for (int k = 0; k < 4; ++k)                                                \
    s[k] = vfma2(czk[k], s[k], vmul2(szk[k], vperp(s[k])));                  \
  _Pragma("unroll")                                                          \
  for (int k = 0; k < 4; ++k) {                                              \
    v2f p = dpp2<QP_XOR2>(s[k]);                                             \
    s[k] = vfma2(cry, s[k], vmul2(sgn0, p));                                 \
  }                                                                          \
  _Pragma("unroll")                                                          \
  for (int k = 0; k < 4; ++k) {                                              \
    v2f p = dpp2<QP_XOR1>(s[k]);                                             \
    s[k] = vfma2(cry, s[k], vmul2(sgn1, p));                                 \
  }                                                                          \
  _Pragma("unroll")                                                          \
  for (int k = 0; k < 2; ++k) {                                              \
    v2f lo = s[k], hi = s[k+2];                                              \
    s[k]   = vfma2(cry, lo, vmul2(nsry, hi));                                \
    s[k+2] = vfma2(sry, lo, vmul2(cry, hi));                                 \
  }                                                                          \
  _Pragma("unroll")                                                          \
  for (int k = 0; k < 4; k += 2) {                                           \
    v2f lo = s[k], hi = s[k+1];                                              \
    s[k]   = vfma2(cry, lo, vmul2(nsry, hi));                                \
    s[k+1] = vfma2(sry, lo, vmul2(cry, hi));                                 \
  }                                                                          \
  { v2f q0 = s[0]*s[0], q1 = s[1]*s[1], q2 = s[2]*s[2], q3 = s[3]*s[3];      \
    float p0 = q0.x + q0.y, p1 = q1.x + q1.y;                                \
    float p2 = q2.x + q2.y, p3 = q3.x + q3.y;                                \
    float s01 = p0 + p1, s23 = p2 + p3;                                      \
    float t_  = s01 + s23;                                                   \
    np0 = sxor(t_, sm0);                                                     \
    np1 = sxor(t_, sm1);                                                     \
    np2 = s01 - s23;                                                         \
    np3 = (p0 - p1) + (p2 - p3);                                             \
  }                                                                          \
} while (0)

// Deferred readout: butterfly + fc1 fold for the PENDING window (pd*, pdWin).
#define BF_FOLD do {                                                         \
  float o0 = pd0, o1 = pd1, o2 = pd2, o3 = pd3;                              \
  o0 += dppf<QP_XOR1>(o0); o0 += dppf<QP_XOR2>(o0);                          \
  o1 += dppf<QP_XOR1>(o1); o1 += dppf<QP_XOR2>(o1);                          \
  o2 += dppf<QP_XOR1>(o2); o2 += dppf<QP_XOR2>(o2);                          \
  o3 += dppf<QP_XOR1>(o3); o3 += dppf<QP_XOR2>(o3);                          \
  const float* wp = swl + pdWin * 4;                                         \
  float4 wv0 = *(const float4*)(wp);                                         \
  float4 wv1 = *(const float4*)(wp + 784);                                   \
  float4 wv2 = *(const float4*)(wp + 1568);                                  \
  float4 wv3 = *(const float4*)(wp + 2352);                                  \
  float4 wv4 = *(const float4*)(wp + 3136);                                  \
  h1[0] = fmaf(wv0.x, o0, fmaf(wv0.y, o1, fmaf(wv0.z, o2, fmaf(wv0.w, o3, h1[0])))); \
  h1[1] = fmaf(wv1.x, o0, fmaf(wv1.y, o1, fmaf(wv1.z, o2, fmaf(wv1.w, o3, h1[1])))); \
  h1[2] = fmaf(wv2.x, o0, fmaf(wv2.y, o1, fmaf(wv2.z, o2, fmaf(wv2.w, o3, h1[2])))); \
  h1[3] = fmaf(wv3.x, o0, fmaf(wv3.y, o1, fmaf(wv3.z, o2, fmaf(wv3.w, o3, h1[3])))); \
  h1[4] = fmaf(wv4.x, o0, fmaf(wv4.y, o1, fmaf(wv4.z, o2, fmaf(wv4.w, o3, h1[4])))); \
} while (0)

#define SHIFT_PEND(WIN)  pd0 = np0; pd1 = np1; pd2 = np2; pd3 = np3; pdWin = (WIN);
#define ROTATE_W  Wc0 = Wn0; Wc1 = Wn1; Wc2 = Wn2; Wc3 = Wn3;

__global__ void __launch_bounds__(256)
quanv_kernel(const float* __restrict__ x,
             const float* __restrict__ crz_t,
             const float* __restrict__ ry_t,
             const float* __restrict__ fc1_w,
             const float* __restrict__ fc1_b,
             const float* __restrict__ fc2_w,
             const float* __restrict__ fc2_b,
             float* __restrict__ out, int B)
{
  __shared__ float sw[20 * 784];
  const int tid = threadIdx.x;
  for (int i = tid; i < (20 * 784) / 4; i += 256)
    ((float4*)sw)[i] = ((const float4*)fc1_w)[i];
  __syncthreads();

  const int l = tid & 3;                       // lane within 4-lane group
  const int b = (blockIdx.x * 256 + tid) >> 2; // element id
  if (b >= B) return;
  const float* img = x + (size_t)b * 784;
  const bool l0 = (l == 0), l1 = (l == 1), l2 = (l == 2);

  // ---- uniform scalar-derived constants ----
  const float theta = crz_t[0];
  const float ryt   = ry_t[0];
  float cry, sry;
  __sincosf(0.5f * ryt, &sry, &cry);
  const float nsry = -sry;
  const float sgn0 = (l & 2) ? sry : -sry;
  const float sgn1 = (l & 1) ? sry : -sry;
  const int sm0 = (l & 2) ? (int)0x80000000 : 0;
  const int sm1 = (l & 1) ? (int)0x80000000 : 0;

  float g0,g1,g2,g3;
  if      (l == 0) { g0= 0.f; g1=-1.f; g2=-1.f; g3=0.f; }
  else if (l == 1) { g0=-1.f; g1=-2.f; g2= 0.f; g3=1.f; }
  else if (l == 2) { g0=-1.f; g1= 0.f; g2=-2.f; g3=1.f; }
  else             { g0= 0.f; g1= 1.f; g2= 1.f; g3=4.f; }
  float czk[4], szk[4];
  __sincosf(0.5f*theta*g0, &szk[0], &czk[0]);
  __sincosf(0.5f*theta*g1, &szk[1], &czk[1]);
  __sincosf(0.5f*theta*g2, &szk[2], &czk[2]);
  __sincosf(0.5f*theta*g3, &szk[3], &czk[3]);

  // state: amp n = 4*l + k; s[k] = (re, im) packed
  v2f s[4];
#pragma unroll
  for (int k = 0; k < 4; ++k) { s[k].x = 0.f; s[k].y = 0.f; }
  if (l == 0) s[0].x = 1.f;

  float h1[5];
#pragma unroll
  for (int j = 0; j < 5; ++j) h1[j] = 0.f;
  const float* swl = sw + 5 * l * 784;

  float P[4][4];
  float a0, a1, a2, a3, a4;
  float Wc0, Wc1, Wc2, Wc3, Wn0, Wn1, Wn2, Wn3;
  float np0, np1, np2, np3;
  float pd0 = 0.f, pd1 = 0.f, pd2 = 0.f, pd3 = 0.f;  // pending readout (0-seeded)
  int pdWin = 0;

  // ================= main rows: wi = 0..12 (h = 4 always) =================
#pragma unroll 1
  for (int wi = 0; wi < 13; ++wi) {
    const float* imgw = img + (2 * wi) * 28;

    // peel wj = 0: fresh load + build only (prev row's pending carries over)
#pragma unroll
    for (int r = 0; r < 4; ++r) {
      float4 v = *(const float4*)(imgw + r * 28);
      P[r][0]=v.x; P[r][1]=v.y; P[r][2]=v.z; P[r][3]=v.w;
    }
    PICK_FULL;
    build_gate(a0, a1, a2, a3, a4, Wc0, Wc1, Wc2, Wc3);

    // prefetch window 1's new columns (cols 4,5)
    float2 Q0 = *(const float2*)(imgw + 0 * 28 + 4);
    float2 Q1 = *(const float2*)(imgw + 1 * 28 + 4);
    float2 Q2 = *(const float2*)(imgw + 2 * 28 + 4);
    float2 Q3 = *(const float2*)(imgw + 3 * 28 + 4);

    // hot loop: wj = 1..12 — branch-free; unroll 4; slide uses prefetched Q,
    // next iteration's Q loads issue here (load-to-use = one full window).
    // Body: build(wj) || apply(wj-1) || deferred butterfly+fold(wj-2).
#pragma unroll 4
    for (int wj = 1; wj <= 12; ++wj) {
      P[0][0]=P[0][2]; P[0][1]=P[0][3]; P[0][2]=Q0.x; P[0][3]=Q0.y;
      P[1][0]=P[1][2]; P[1][1]=P[1][3]; P[1][2]=Q1.x; P[1][3]=Q1.y;
      P[2][0]=P[2][2]; P[2][1]=P[2][3]; P[2][2]=Q2.x; P[2][3]=Q2.y;
      P[3][0]=P[3][2]; P[3][1]=P[3][3]; P[3][2]=Q3.x; P[3][3]=Q3.y;
      const int c0n = (wj < 12) ? (2 * wj + 4) : 24;   // clamped: last prefetch unused
      Q0 = *(const float2*)(imgw + 0 * 28 + c0n);
      Q1 = *(const float2*)(imgw + 1 * 28 + c0n);
      Q2 = *(const float2*)(imgw + 2 * 28 + c0n);
      Q3 = *(const float2*)(imgw + 3 * 28 + c0n);
      PICK_FULL;
      build_gate(a0, a1, a2, a3, a4, Wn0, Wn1, Wn2, Wn3);
      APPLY_Z;                                   // window wj-1 -> np
      BF_FOLD;                                   // window wj-2 (or older)
      SHIFT_PEND(wi * 14 + wj - 1);
      ROTATE_W;
    }

    // peel wj = 13: zero-fill slide
#pragma unroll
    for (int r = 0; r < 4; ++r) {
      P[r][0] = P[r][2]; P[r][1] = P[r][3]; P[r][2] = 0.f; P[r][3] = 0.f;
    }
    PICK_W2;
    build_gate(a0, a1, a2, a3, a4, Wn0, Wn1, Wn2, Wn3);
    APPLY_Z;                                     // window 12
    BF_FOLD;                                     // window 11
    SHIFT_PEND(wi * 14 + 12);
    ROTATE_W;
    APPLY_Z;                                     // window 13
    BF_FOLD;                                     // window 12
    SHIFT_PEND(wi * 14 + 13);
  }

  // ================= tail row: wi = 13 (h = 2) =================
  {
    const float* imgw = img + 26 * 28;
#pragma unroll
    for (int r = 0; r < 2; ++r) {
      float4 v = *(const float4*)(imgw + r * 28);
      P[r][0]=v.x; P[r][1]=v.y; P[r][2]=v.z; P[r][3]=v.w;
    }
#pragma unroll
    for (int r = 2; r < 4; ++r) { P[r][0]=0.f; P[r][1]=0.f; P[r][2]=0.f; P[r][3]=0.f; }
    PICK_H2;
    build_gate(a0, a1, a2, a3, a4, Wc0, Wc1, Wc2, Wc3);

    float2 Q0 = *(const float2*)(imgw + 4);
    float2 Q1 = *(const float2*)(imgw + 28 + 4);

#pragma unroll 4
    for (int wj = 1; wj <= 12; ++wj) {
      P[0][0]=P[0][2]; P[0][1]=P[0][3]; P[0][2]=Q0.x; P[0][3]=Q0.y;
      P[1][0]=P[1][2]; P[1][1]=P[1][3]; P[1][2]=Q1.x; P[1][3]=Q1.y;
      const int c0n = (wj < 12) ? (2 * wj + 4) : 24;
      Q0 = *(const float2*)(imgw + c0n);
      Q1 = *(const float2*)(imgw + 28 + c0n);
      PICK_H2;
      build_gate(a0, a1, a2, a3, a4, Wn0, Wn1, Wn2, Wn3);
      APPLY_Z;
      BF_FOLD;
      SHIFT_PEND(182 + wj - 1);
      ROTATE_W;
    }

    P[0][0]=P[0][2]; P[0][1]=P[0][3]; P[0][2]=0.f; P[0][3]=0.f;
    P[1][0]=P[1][2]; P[1][1]=P[1][3]; P[1][2]=0.f; P[1][3]=0.f;
    PICK_22;
    build_gate(a0, a1, a2, a3, a4, Wn0, Wn1, Wn2, Wn3);
    APPLY_Z;                                     // window 194
    BF_FOLD;                                     // window 193
    SHIFT_PEND(182 + 12);
    ROTATE_W;
    APPLY_Z;                                     // window 195
    BF_FOLD;                                     // window 194
    SHIFT_PEND(182 + 13);
  }

  // drain the pipeline: fold window 195
  BF_FOLD;

  // ---- epilogue: bias + leaky relu + fc2, reduce over group ----
  float pa = 0.f, pb = 0.f;
#pragma unroll
  for (int j = 0; j < 5; ++j) {
    const int r = 5 * l + j;
    float v = h1[j] + fc1_b[r];
    v = (v > 0.f) ? v : 0.1f * v;
    pa = fmaf(fc2_w[r],      v, pa);
    pb = fmaf(fc2_w[20 + r], v, pb);
  }
  pa += dppf<QP_XOR1>(pa); pa += dppf<QP_XOR2>(pa);
  pb += dppf<QP_XOR1>(pb); pb += dppf<QP_XOR2>(pb);
  if (l == 0) {
    float2 res; res.x = pa + fc2_b[0]; res.y = pb + fc2_b[1];
    *(float2*)(out + (size_t)b * 2) = res;
  }
}

extern "C" void kernel_launch(void* const* d_in, const int* in_sizes, int n_in,
                              void* d_out, int out_size, void* d_ws, size_t ws_size,
                              hipStream_t stream) {
  const float* x      = (const float*)d_in[0];
  const float* crz_t  = (const float*)d_in[1];
  const float* ry_t   = (const float*)d_in[2];
  const float* fc1_w  = (const float*)d_in[3];
  const float* fc1_b  = (const float*)d_in[4];
  const float* fc2_w  = (const float*)d_in[5];
  const float* fc2_b  = (const float*)d_in[6];
  float* out = (float*)d_out;
  const int B = in_sizes[0] / 784;
  const int grid = (B * 4 + 255) / 256;
  quanv_kernel<<<grid, 256, 0, stream>>>(x, crz_t, ry_t, fc1_w, fc1_b,
                                         fc2_w, fc2_b, out, B);
}